// Round 3
// baseline (465.880 us; speedup 1.0000x reference)
//
#include <hip/hip_runtime.h>
#include <math.h>

#define NTH 256
#define LAM 0.01f
#define WS_WT_BYTES 589824   // 4 planes * 8 blocks * 96*96 * 2B (bf16 W^T)

typedef __attribute__((ext_vector_type(8))) short short8;
typedef __attribute__((ext_vector_type(8))) unsigned short ushort8;
typedef __attribute__((ext_vector_type(4))) float f32x4;

__device__ __forceinline__ ushort f2bf(float f) {
    union { float f; unsigned u; } c; c.f = f;
    unsigned u = c.u;
    u += 0x7fffu + ((u >> 16) & 1u);   // round-to-nearest-even
    return (ushort)(u >> 16);
}

// LDS index padding: breaks power-of-2 stride bank conflicts (float2 elems,
// 32 banks -> pad one float2 every 32).
__device__ __forceinline__ int pad(int i) { return i + (i >> 5); }
#define FFT_LDS_SZ 2112   // pad(2047)=2110, round up

// ---------------------------------------------------------------------------
// Stockham complex FFT of length 2048 in LDS: 5 radix-4 stages + 1 radix-2.
// ---------------------------------------------------------------------------
__device__ __forceinline__ float2* fft2048_stockham(float2* bufA, float2* bufB,
                                                    int tid, float sign) {
    float2* src = bufA;
    float2* dst = bufB;
#pragma unroll
    for (int s = 0; s < 5; ++s) {
        const int Ns = 1 << (2 * s);
        const float w0 = sign * (float)M_PI / (float)(2 * Ns);
#pragma unroll
        for (int u = tid; u < 512; u += NTH) {
            const int r = u & (Ns - 1);
            float2 x0 = src[pad(u)];
            float2 x1 = src[pad(u + 512)];
            float2 x2 = src[pad(u + 1024)];
            float2 x3 = src[pad(u + 1536)];
            float ang = w0 * (float)r;
            float s1, c1;
            __sincosf(ang, &s1, &c1);
            float c2 = c1 * c1 - s1 * s1, s2 = 2.f * c1 * s1;
            float c3 = c2 * c1 - s2 * s1, s3 = c2 * s1 + s2 * c1;
            float2 t1 = make_float2(x1.x * c1 - x1.y * s1, x1.x * s1 + x1.y * c1);
            float2 t2 = make_float2(x2.x * c2 - x2.y * s2, x2.x * s2 + x2.y * c2);
            float2 t3 = make_float2(x3.x * c3 - x3.y * s3, x3.x * s3 + x3.y * c3);
            float2 apc = make_float2(x0.x + t2.x, x0.y + t2.y);
            float2 amc = make_float2(x0.x - t2.x, x0.y - t2.y);
            float2 bpd = make_float2(t1.x + t3.x, t1.y + t3.y);
            float2 bmd = make_float2(t1.x - t3.x, t1.y - t3.y);
            float2 e = make_float2(-sign * bmd.y, sign * bmd.x);
            const int d = ((u - r) << 2) + r;
            dst[pad(d)]          = make_float2(apc.x + bpd.x, apc.y + bpd.y);
            dst[pad(d + Ns)]     = make_float2(amc.x + e.x,   amc.y + e.y);
            dst[pad(d + 2 * Ns)] = make_float2(apc.x - bpd.x, apc.y - bpd.y);
            dst[pad(d + 3 * Ns)] = make_float2(amc.x - e.x,   amc.y - e.y);
        }
        __syncthreads();
        float2* t = src; src = dst; dst = t;
    }
    const float w1 = sign * (float)M_PI / 1024.0f;
    for (int u = tid; u < 1024; u += NTH) {
        float2 a = src[pad(u)];
        float2 b = src[pad(u + 1024)];
        float ang = w1 * (float)u;
        float sn, cn;
        __sincosf(ang, &sn, &cn);
        float bwx = b.x * cn - b.y * sn;
        float bwy = b.x * sn + b.y * cn;
        dst[pad(u)]        = make_float2(a.x + bwx, a.y + bwy);
        dst[pad(u + 1024)] = make_float2(a.x - bwx, a.y - bwy);
    }
    __syncthreads();
    return dst;
}

// ---------------------------------------------------------------------------
// Forward rfft per row (ortho), packed output (4096 floats / row).
// ---------------------------------------------------------------------------
__global__ __launch_bounds__(NTH) void k_rfft_fwd(const float* __restrict__ x,
                                                  float* __restrict__ out) {
    __shared__ float2 bufA[FFT_LDS_SZ];
    __shared__ float2 bufB[FFT_LDS_SZ];
    const int row = blockIdx.x;
    const float* xr = x + (size_t)row * 4096;
    float* orow = out + (size_t)row * 4096;
    const int tid = threadIdx.x;

    for (int t = tid; t < 2048; t += NTH)
        bufA[pad(t)] = *(const float2*)(xr + 2 * t);
    __syncthreads();

    float2* Z = fft2048_stockham(bufA, bufB, tid, -1.0f);

    const float scale = 1.0f / 64.0f;
    for (int k = tid; k <= 2048; k += NTH) {
        float2 zk = Z[pad(k & 2047)];
        float2 zn = Z[pad((2048 - k) & 2047)];
        float Ar = 0.5f * (zk.x + zn.x), Ai = 0.5f * (zk.y - zn.y);
        float Br = 0.5f * (zk.x - zn.x), Bi = 0.5f * (zk.y + zn.y);
        float ang = -(float)M_PI * (float)k / 2048.0f;
        float s, c;
        __sincosf(ang, &s, &c);
        float wBr = c * Br - s * Bi;
        float wBi = c * Bi + s * Br;
        float Xr = (Ar + wBi) * scale;
        float Xi = (Ai - wBr) * scale;
        if (k == 0)          orow[0] = Xr;
        else if (k == 2048)  orow[1] = Xr;
        else                 *(float2*)(orow + 2 * k) = make_float2(Xr, Xi);
    }
}

// ---------------------------------------------------------------------------
// Weight preprocessing: fp32 W[a][n][i][o] -> bf16 W^T in ws: [a][n][o][i].
// ---------------------------------------------------------------------------
__global__ __launch_bounds__(NTH) void k_prep(
    const float* __restrict__ w1_re, const float* __restrict__ w1_im,
    const float* __restrict__ w2_re, const float* __restrict__ w2_im,
    ushort* __restrict__ wt) {
    int gid = blockIdx.x * NTH + threadIdx.x;   // 0 .. 294911
    if (gid >= 294912) return;
    int a   = gid / 73728;
    int rem = gid - a * 73728;
    int n   = rem / 9216;
    int r2  = rem - n * 9216;
    int o   = r2 / 96;
    int i   = r2 - o * 96;
    const float* src = (a == 0) ? w1_re : (a == 1) ? w1_im : (a == 2) ? w2_re : w2_im;
    wt[gid] = f2bf(src[(n * 96 + i) * 96 + o]);
}

// ---------------------------------------------------------------------------
// MFMA mixer v4: barrier-free, 32 modes/wave (weight frags reused 2x),
// layer-2 operands SWAPPED so C = [chan][mode] -> fully coalesced 128-B
// float2 stores (16 consecutive modes per 16-lane group).
// Grid (17 m-tiles of 128, 8 blocks, 16 batch) x 256 thr (4 waves).
// ---------------------------------------------------------------------------
__global__ __launch_bounds__(NTH, 3) void k_mix4(
    float* __restrict__ io, const ushort* __restrict__ wt,
    const float* __restrict__ b1_re, const float* __restrict__ b1_im,
    const float* __restrict__ b2_re, const float* __restrict__ b2_im) {
    __shared__ __align__(16) ushort xb[2][128][104];   // 53248 B

    const int mt = blockIdx.x;
    const int n  = blockIdx.y;
    const int b  = blockIdx.z;
    const int tid  = threadIdx.x;
    const int lane = tid & 63;
    const int wv   = tid >> 6;
    const int m0 = mt * 128;
    const int ws0 = wv * 32;              // wave's private 32-row stripe
    float* base = io + ((size_t)b * 768 + (size_t)n * 96) * 4096;

    const int lc = lane & 15;
    const int hi = lane >> 4;
    const int kl = 8 * hi;

    // ---- per-wave stage of own 32-mode stripe (no barrier needed)
    {
        const int mm = lc;                 // mode within 16-tile
#pragma unroll
        for (int t = 0; t < 2; ++t) {
            const int mrow = ws0 + t * 16 + mm;
            const int m = m0 + mrow;
            for (int i = hi; i < 96; i += 4) {
                const float* row = base + (size_t)i * 4096;
                float re = 0.f, im = 0.f;
                if (m == 0)          { re = row[0]; }
                else if (m == 2048)  { re = row[1]; }
                else if (m < 2048)   { float2 v = *(const float2*)(row + 2 * m); re = v.x; im = v.y; }
                xb[0][mrow][i] = f2bf(re);
                xb[1][mrow][i] = f2bf(im);
            }
        }
    }

    const ushort* wn  = wt + (size_t)n * 9216;        // w1_re^T; +73728 per plane
    const ushort* wn2 = wn + 2 * 73728;               // w2_re^T

    float b1r[6], b1i[6];
#pragma unroll
    for (int nt = 0; nt < 6; ++nt) {
        b1r[nt] = b1_re[n * 96 + nt * 16 + lc];
        b1i[nt] = b1_im[n * 96 + nt * 16 + lc];
    }

    f32x4 accR[2][6], accI[2][6];
    const f32x4 zero = {0.f, 0.f, 0.f, 0.f};
#pragma unroll
    for (int t = 0; t < 2; ++t)
#pragma unroll
        for (int nt = 0; nt < 6; ++nt) { accR[t][nt] = zero; accI[t][nt] = zero; }

    // ---- layer 1 (unswapped: C[mode][chan]), weight frags shared by 2 tiles
#pragma unroll
    for (int kk = 0; kk < 3; ++kk) {
        const int k0 = kk * 32 + kl;
        short8 arA = *(const short8*)&xb[0][ws0 + lc][k0];
        short8 aiA = *(const short8*)&xb[1][ws0 + lc][k0];
        short8 arB = *(const short8*)&xb[0][ws0 + 16 + lc][k0];
        short8 aiB = *(const short8*)&xb[1][ws0 + 16 + lc][k0];
        short8 naiA, naiB;
#pragma unroll
        for (int j = 0; j < 8; ++j) { naiA[j] = aiA[j] ^ (short)0x8000; naiB[j] = aiB[j] ^ (short)0x8000; }
#pragma unroll
        for (int nt = 0; nt < 6; ++nt) {
            const ushort* wp = wn + (nt * 16 + lc) * 96 + k0;
            short8 br = *(const short8*)(wp);            // w1_re^T
            short8 bi = *(const short8*)(wp + 73728);    // w1_im^T
            accR[0][nt] = __builtin_amdgcn_mfma_f32_16x16x32_bf16(arA,  br, accR[0][nt], 0, 0, 0);
            accR[0][nt] = __builtin_amdgcn_mfma_f32_16x16x32_bf16(naiA, bi, accR[0][nt], 0, 0, 0);
            accI[0][nt] = __builtin_amdgcn_mfma_f32_16x16x32_bf16(arA,  bi, accI[0][nt], 0, 0, 0);
            accI[0][nt] = __builtin_amdgcn_mfma_f32_16x16x32_bf16(aiA,  br, accI[0][nt], 0, 0, 0);
            accR[1][nt] = __builtin_amdgcn_mfma_f32_16x16x32_bf16(arB,  br, accR[1][nt], 0, 0, 0);
            accR[1][nt] = __builtin_amdgcn_mfma_f32_16x16x32_bf16(naiB, bi, accR[1][nt], 0, 0, 0);
            accI[1][nt] = __builtin_amdgcn_mfma_f32_16x16x32_bf16(arB,  bi, accI[1][nt], 0, 0, 0);
            accI[1][nt] = __builtin_amdgcn_mfma_f32_16x16x32_bf16(aiB,  br, accI[1][nt], 0, 0, 0);
        }
    }
    // crelu -> h into own stripe (same-wave LDS dependency only)
#pragma unroll
    for (int t = 0; t < 2; ++t)
#pragma unroll
        for (int nt = 0; nt < 6; ++nt) {
#pragma unroll
            for (int q = 0; q < 4; ++q) {
                int mrow = ws0 + t * 16 + 4 * hi + q;
                xb[0][mrow][nt * 16 + lc] = f2bf(fmaxf(accR[t][nt][q] + b1r[nt], 0.f));
                xb[1][mrow][nt * 16 + lc] = f2bf(fmaxf(accI[t][nt][q] + b1i[nt], 0.f));
            }
        }

    // ---- layer 2, SWAPPED operands: C[chan][mode]
#pragma unroll
    for (int t = 0; t < 2; ++t)
#pragma unroll
        for (int nt = 0; nt < 6; ++nt) { accR[t][nt] = zero; accI[t][nt] = zero; }
#pragma unroll
    for (int kk = 0; kk < 3; ++kk) {
        const int k0 = kk * 32 + kl;
        short8 arA = *(const short8*)&xb[0][ws0 + lc][k0];
        short8 aiA = *(const short8*)&xb[1][ws0 + lc][k0];
        short8 arB = *(const short8*)&xb[0][ws0 + 16 + lc][k0];
        short8 aiB = *(const short8*)&xb[1][ws0 + 16 + lc][k0];
        short8 naiA, naiB;
#pragma unroll
        for (int j = 0; j < 8; ++j) { naiA[j] = aiA[j] ^ (short)0x8000; naiB[j] = aiB[j] ^ (short)0x8000; }
#pragma unroll
        for (int nt = 0; nt < 6; ++nt) {
            const ushort* wp = wn2 + (nt * 16 + lc) * 96 + k0;
            short8 br = *(const short8*)(wp);            // w2_re^T
            short8 bi = *(const short8*)(wp + 73728);    // w2_im^T
            // D[chan][mode] = sum_k W^T[chan][k] * h[mode][k]
            accR[0][nt] = __builtin_amdgcn_mfma_f32_16x16x32_bf16(br, arA,  accR[0][nt], 0, 0, 0);
            accR[0][nt] = __builtin_amdgcn_mfma_f32_16x16x32_bf16(bi, naiA, accR[0][nt], 0, 0, 0);
            accI[0][nt] = __builtin_amdgcn_mfma_f32_16x16x32_bf16(bi, arA,  accI[0][nt], 0, 0, 0);
            accI[0][nt] = __builtin_amdgcn_mfma_f32_16x16x32_bf16(br, aiA,  accI[0][nt], 0, 0, 0);
            accR[1][nt] = __builtin_amdgcn_mfma_f32_16x16x32_bf16(br, arB,  accR[1][nt], 0, 0, 0);
            accR[1][nt] = __builtin_amdgcn_mfma_f32_16x16x32_bf16(bi, naiB, accR[1][nt], 0, 0, 0);
            accI[1][nt] = __builtin_amdgcn_mfma_f32_16x16x32_bf16(bi, arB,  accI[1][nt], 0, 0, 0);
            accI[1][nt] = __builtin_amdgcn_mfma_f32_16x16x32_bf16(br, aiB,  accI[1][nt], 0, 0, 0);
        }
    }

    // softshrink + coalesced packed store: lane (hi,lc,q): chan=nt*16+4hi+q,
    // mode=m0+ws0+t*16+lc -> 16 consecutive float2 per 16-lane group.
#pragma unroll
    for (int t = 0; t < 2; ++t) {
        const int m = m0 + ws0 + t * 16 + lc;
#pragma unroll
        for (int nt = 0; nt < 6; ++nt) {
            f32x4 vbr = *(const f32x4*)(b2_re + n * 96 + nt * 16 + 4 * hi);
            f32x4 vbi = *(const f32x4*)(b2_im + n * 96 + nt * 16 + 4 * hi);
#pragma unroll
            for (int q = 0; q < 4; ++q) {
                float vr = accR[t][nt][q] + vbr[q];
                float vi = accI[t][nt][q] + vbi[q];
                float sr = copysignf(fmaxf(fabsf(vr) - LAM, 0.f), vr);
                float si = copysignf(fmaxf(fabsf(vi) - LAM, 0.f), vi);
                float* row = base + (size_t)(nt * 16 + 4 * hi + q) * 4096;
                if (m == 0)          row[0] = sr;
                else if (m == 2048)  row[1] = sr;
                else if (m < 2048)   *(float2*)(row + 2 * m) = make_float2(sr, si);
            }
        }
    }
}

// ---------------------------------------------------------------------------
// Fallback mixer (no ws dependency).
// ---------------------------------------------------------------------------
__global__ __launch_bounds__(NTH) void k_mix_fallback(
    float* __restrict__ io,
    const float* __restrict__ w1_re, const float* __restrict__ w1_im,
    const float* __restrict__ w2_re, const float* __restrict__ w2_im,
    const float* __restrict__ b1_re, const float* __restrict__ b1_im,
    const float* __restrict__ b2_re, const float* __restrict__ b2_im) {
    __shared__ __align__(16) ushort xb[2][64][96];
    __shared__ __align__(16) ushort wb[2][96][104];

    const int mt = blockIdx.x;
    const int n  = blockIdx.y;
    const int b  = blockIdx.z;
    const int tid = threadIdx.x;
    const int lane = tid & 63;
    const int wv   = tid >> 6;
    const int m0 = mt * 64;
    float* base = io + ((size_t)b * 768 + (size_t)n * 96) * 4096;

    for (int idx = tid; idx < 96 * 64; idx += NTH) {
        int i = idx >> 6, mm = idx & 63;
        int m = m0 + mm;
        const float* row = base + (size_t)i * 4096;
        float re = 0.f, im = 0.f;
        if (m == 0) { re = row[0]; }
        else if (m == 2048) { re = row[1]; }
        else if (m < 2048) { float2 v = *(const float2*)(row + 2 * m); re = v.x; im = v.y; }
        xb[0][mm][i] = f2bf(re);
        xb[1][mm][i] = f2bf(im);
    }
    const float* W1r = w1_re + (size_t)n * 9216;
    const float* W1i = w1_im + (size_t)n * 9216;
    for (int idx = tid; idx < 9216; idx += NTH) {
        int i = idx / 96, o = idx - i * 96;
        wb[0][o][i] = f2bf(W1r[idx]);
        wb[1][o][i] = f2bf(W1i[idx]);
    }
    const int lc = lane & 15;
    float b1r[6], b1i[6], b2r[6], b2i[6];
#pragma unroll
    for (int nt = 0; nt < 6; ++nt) {
        b1r[nt] = b1_re[n * 96 + nt * 16 + lc];
        b1i[nt] = b1_im[n * 96 + nt * 16 + lc];
        b2r[nt] = b2_re[n * 96 + nt * 16 + lc];
        b2i[nt] = b2_im[n * 96 + nt * 16 + lc];
    }
    __syncthreads();

    const int mw = wv * 16;
    const int klr = 8 * (lane >> 4);
    const int mrow = mw + lc;

    f32x4 accR[6], accI[6];
    const f32x4 zero = {0.f, 0.f, 0.f, 0.f};
#pragma unroll
    for (int nt = 0; nt < 6; ++nt) { accR[nt] = zero; accI[nt] = zero; }

#pragma unroll
    for (int kk = 0; kk < 3; ++kk) {
        int k0 = kk * 32 + klr;
        short8 ar = *(const short8*)&xb[0][mrow][k0];
        short8 ai = *(const short8*)&xb[1][mrow][k0];
        short8 nai;
#pragma unroll
        for (int j = 0; j < 8; ++j) nai[j] = ai[j] ^ (short)0x8000;
#pragma unroll
        for (int nt = 0; nt < 6; ++nt) {
            short8 br = *(const short8*)&wb[0][nt * 16 + lc][k0];
            short8 bi = *(const short8*)&wb[1][nt * 16 + lc][k0];
            accR[nt] = __builtin_amdgcn_mfma_f32_16x16x32_bf16(ar,  br, accR[nt], 0, 0, 0);
            accR[nt] = __builtin_amdgcn_mfma_f32_16x16x32_bf16(nai, bi, accR[nt], 0, 0, 0);
            accI[nt] = __builtin_amdgcn_mfma_f32_16x16x32_bf16(ar,  bi, accI[nt], 0, 0, 0);
            accI[nt] = __builtin_amdgcn_mfma_f32_16x16x32_bf16(ai,  br, accI[nt], 0, 0, 0);
        }
    }
#pragma unroll
    for (int nt = 0; nt < 6; ++nt) {
#pragma unroll
        for (int q = 0; q < 4; ++q) {
            int m = mw + 4 * (lane >> 4) + q;
            float hr = fmaxf(accR[nt][q] + b1r[nt], 0.f);
            float hi = fmaxf(accI[nt][q] + b1i[nt], 0.f);
            xb[0][m][nt * 16 + lc] = f2bf(hr);
            xb[1][m][nt * 16 + lc] = f2bf(hi);
        }
    }
    __syncthreads();

    const float* W2r = w2_re + (size_t)n * 9216;
    const float* W2i = w2_im + (size_t)n * 9216;
    for (int idx = tid; idx < 9216; idx += NTH) {
        int i = idx / 96, o = idx - i * 96;
        wb[0][o][i] = f2bf(W2r[idx]);
        wb[1][o][i] = f2bf(W2i[idx]);
    }
    __syncthreads();

#pragma unroll
    for (int nt = 0; nt < 6; ++nt) { accR[nt] = zero; accI[nt] = zero; }
#pragma unroll
    for (int kk = 0; kk < 3; ++kk) {
        int k0 = kk * 32 + klr;
        short8 ar = *(const short8*)&xb[0][mrow][k0];
        short8 ai = *(const short8*)&xb[1][mrow][k0];
        short8 nai;
#pragma unroll
        for (int j = 0; j < 8; ++j) nai[j] = ai[j] ^ (short)0x8000;
#pragma unroll
        for (int nt = 0; nt < 6; ++nt) {
            short8 br = *(const short8*)&wb[0][nt * 16 + lc][k0];
            short8 bi = *(const short8*)&wb[1][nt * 16 + lc][k0];
            accR[nt] = __builtin_amdgcn_mfma_f32_16x16x32_bf16(ar,  br, accR[nt], 0, 0, 0);
            accR[nt] = __builtin_amdgcn_mfma_f32_16x16x32_bf16(nai, bi, accR[nt], 0, 0, 0);
            accI[nt] = __builtin_amdgcn_mfma_f32_16x16x32_bf16(ar,  bi, accI[nt], 0, 0, 0);
            accI[nt] = __builtin_amdgcn_mfma_f32_16x16x32_bf16(ai,  br, accI[nt], 0, 0, 0);
        }
    }
#pragma unroll
    for (int nt = 0; nt < 6; ++nt) {
#pragma unroll
        for (int q = 0; q < 4; ++q) {
            int m = m0 + mw + 4 * (lane >> 4) + q;
            float vr = accR[nt][q] + b2r[nt];
            float vi = accI[nt][q] + b2i[nt];
            float sr = copysignf(fmaxf(fabsf(vr) - LAM, 0.f), vr);
            float si = copysignf(fmaxf(fabsf(vi) - LAM, 0.f), vi);
            float* row = base + (size_t)(nt * 16 + lc) * 4096;
            if (m == 0)          row[0] = sr;
            else if (m == 2048)  row[1] = sr;
            else if (m < 2048)   *(float2*)(row + 2 * m) = make_float2(sr, si);
        }
    }
}

// ---------------------------------------------------------------------------
// Inverse rfft per row (ortho) + residual add, in-place on packed spectrum.
// ---------------------------------------------------------------------------
__global__ __launch_bounds__(NTH) void k_irfft_add(const float* __restrict__ x,
                                                   float* __restrict__ io) {
    __shared__ float2 bufA[FFT_LDS_SZ];
    __shared__ float2 bufB[FFT_LDS_SZ];
    const int row = blockIdx.x;
    const float* xr = x + (size_t)row * 4096;
    float* orow = io + (size_t)row * 4096;
    const int tid = threadIdx.x;
    const float scale = 1.0f / 32.0f;

    for (int k = tid; k < 2048; k += NTH) {
        float Xr, Xi, Yr, Yi;
        if (k == 0) {
            Xr = orow[0]; Xi = 0.f; Yr = orow[1]; Yi = 0.f;
        } else {
            float2 a  = *(const float2*)(orow + 2 * k);
            float2 bq = *(const float2*)(orow + 2 * (2048 - k));
            Xr = a.x; Xi = a.y; Yr = bq.x; Yi = bq.y;
        }
        float Fer = 0.5f * (Xr + Yr), Fei = 0.5f * (Xi - Yi);
        float Dr  = 0.5f * (Xr - Yr), Di  = 0.5f * (Xi + Yi);
        float ang = (float)M_PI * (float)k / 2048.0f;
        float s, c;
        __sincosf(ang, &s, &c);
        float For = c * Dr - s * Di;
        float Foi = c * Di + s * Dr;
        bufA[pad(k)] = make_float2((Fer - Foi) * scale, (Fei + For) * scale);
    }
    __syncthreads();

    float2* Zt = fft2048_stockham(bufA, bufB, tid, 1.0f);

    for (int t = tid; t < 2048; t += NTH) {
        float2 z  = Zt[pad(t)];
        float2 xv = *(const float2*)(xr + 2 * t);
        *(float2*)(orow + 2 * t) = make_float2(z.x + xv.x, z.y + xv.y);
    }
}

// ---------------------------------------------------------------------------
extern "C" void kernel_launch(void* const* d_in, const int* in_sizes, int n_in,
                              void* d_out, int out_size, void* d_ws, size_t ws_size,
                              hipStream_t stream) {
    const float* x     = (const float*)d_in[0];
    const float* w1_re = (const float*)d_in[1];
    const float* w1_im = (const float*)d_in[2];
    const float* w2_re = (const float*)d_in[3];
    const float* w2_im = (const float*)d_in[4];
    const float* b1_re = (const float*)d_in[5];
    const float* b1_im = (const float*)d_in[6];
    const float* b2_re = (const float*)d_in[7];
    const float* b2_im = (const float*)d_in[8];
    float* out = (float*)d_out;

    k_rfft_fwd<<<12288, NTH, 0, stream>>>(x, out);
    if (ws_size >= (size_t)WS_WT_BYTES) {
        ushort* wt = (ushort*)d_ws;
        k_prep<<<(294912 + NTH - 1) / NTH, NTH, 0, stream>>>(w1_re, w1_im, w2_re, w2_im, wt);
        k_mix4<<<dim3(17, 8, 16), NTH, 0, stream>>>(out, wt, b1_re, b1_im, b2_re, b2_im);
    } else {
        k_mix_fallback<<<dim3(33, 8, 16), NTH, 0, stream>>>(out, w1_re, w1_im, w2_re, w2_im,
                                                            b1_re, b1_im, b2_re, b2_im);
    }
    k_irfft_add<<<12288, NTH, 0, stream>>>(x, out);
}

// Round 4
// 427.401 us; speedup vs baseline: 1.0900x; 1.0900x over previous
//
#include <hip/hip_runtime.h>
#include <math.h>

#define NTH 256
#define LAM 0.01f
#define WS_WT_BYTES 589824   // 4 planes * 8 blocks * 96*96 * 2B (bf16 W^T)

typedef __attribute__((ext_vector_type(8))) short short8;
typedef __attribute__((ext_vector_type(8))) unsigned short ushort8;
typedef __attribute__((ext_vector_type(4))) float f32x4;

__device__ __forceinline__ ushort f2bf(float f) {
    union { float f; unsigned u; } c; c.f = f;
    unsigned u = c.u;
    u += 0x7fffu + ((u >> 16) & 1u);   // round-to-nearest-even
    return (ushort)(u >> 16);
}

// LDS index padding: one extra float2 every 8 -> radix-8's stride-8 scatter
// becomes stride-9 (16 distinct bank-pairs = minimum phases for b64).
__device__ __forceinline__ int pad(int i) { return i + (i >> 3); }
#define FFT_LDS_SZ 2304   // pad(2047)=2302, round up

// ---- complex helpers -------------------------------------------------------
__device__ __forceinline__ float2 cadd(float2 a, float2 b) { return make_float2(a.x + b.x, a.y + b.y); }
__device__ __forceinline__ float2 csub(float2 a, float2 b) { return make_float2(a.x - b.x, a.y - b.y); }
__device__ __forceinline__ float2 cmul(float2 a, float2 b) { return make_float2(a.x * b.x - a.y * b.y, a.x * b.y + a.y * b.x); }
__device__ __forceinline__ float2 cjrot(float2 a, float sign) { return make_float2(-sign * a.y, sign * a.x); } // sign*i*a

// ---------------------------------------------------------------------------
// Stockham mixed-radix FFT of length 2048: 3 radix-8 stages + 1 radix-4.
// 4 LDS round-trips / 4 barriers (was 6/6). One sincos per radix-8 butterfly;
// w^2..w^7 by chained complex mults.
// ---------------------------------------------------------------------------
__device__ __forceinline__ void radix8_stage(const float2* __restrict__ src,
                                             float2* __restrict__ dst,
                                             int tid, int Ns, float sign) {
    const int u = tid;                       // 256 butterflies, 256 threads
    const int r = u & (Ns - 1);
    float2 t0 = src[pad(u)];
    float2 t1 = src[pad(u + 256)];
    float2 t2 = src[pad(u + 512)];
    float2 t3 = src[pad(u + 768)];
    float2 t4 = src[pad(u + 1024)];
    float2 t5 = src[pad(u + 1280)];
    float2 t6 = src[pad(u + 1536)];
    float2 t7 = src[pad(u + 1792)];
    if (Ns > 1) {
        float ang = sign * ((float)M_PI / (4.0f * (float)Ns)) * (float)r;  // 2*pi*r/(8*Ns)
        float s1, c1;
        __sincosf(ang, &s1, &c1);
        float2 w1 = make_float2(c1, s1);
        float2 w2 = cmul(w1, w1);
        float2 w3 = cmul(w2, w1);
        float2 w4 = cmul(w2, w2);
        float2 w5 = cmul(w4, w1);
        float2 w6 = cmul(w4, w2);
        float2 w7 = cmul(w4, w3);
        t1 = cmul(t1, w1); t2 = cmul(t2, w2); t3 = cmul(t3, w3);
        t4 = cmul(t4, w4); t5 = cmul(t5, w5); t6 = cmul(t6, w6);
        t7 = cmul(t7, w7);
    }
    // even 4-pt DFT on (t0,t2,t4,t6)
    float2 apc = cadd(t0, t4), amc = csub(t0, t4);
    float2 bpd = cadd(t2, t6), bmd = csub(t2, t6);
    float2 e0 = cadd(apc, bpd), e2 = csub(apc, bpd);
    float2 jb = cjrot(bmd, sign);
    float2 e1 = cadd(amc, jb), e3 = csub(amc, jb);
    // odd 4-pt DFT on (t1,t3,t5,t7)
    float2 apc2 = cadd(t1, t5), amc2 = csub(t1, t5);
    float2 bpd2 = cadd(t3, t7), bmd2 = csub(t3, t7);
    float2 o0 = cadd(apc2, bpd2), o2 = csub(apc2, bpd2);
    float2 jb2 = cjrot(bmd2, sign);
    float2 o1 = cadd(amc2, jb2), o3 = csub(amc2, jb2);
    // twiddle odd results by W8^q
    const float H = 0.70710678118654752f;
    o1 = cmul(o1, make_float2(H, sign * H));
    o2 = cjrot(o2, sign);
    o3 = cmul(o3, make_float2(-H, sign * H));
    const int d = ((u - r) << 3) + r;
    dst[pad(d)]          = cadd(e0, o0);
    dst[pad(d + Ns)]     = cadd(e1, o1);
    dst[pad(d + 2 * Ns)] = cadd(e2, o2);
    dst[pad(d + 3 * Ns)] = cadd(e3, o3);
    dst[pad(d + 4 * Ns)] = csub(e0, o0);
    dst[pad(d + 5 * Ns)] = csub(e1, o1);
    dst[pad(d + 6 * Ns)] = csub(e2, o2);
    dst[pad(d + 7 * Ns)] = csub(e3, o3);
}

__device__ __forceinline__ void radix4_final(const float2* __restrict__ src,
                                             float2* __restrict__ dst,
                                             int tid, float sign) {
    // Ns = 512: r = u, d = u; contiguous in/out.
    for (int u = tid; u < 512; u += NTH) {
        float2 x0 = src[pad(u)];
        float2 x1 = src[pad(u + 512)];
        float2 x2 = src[pad(u + 1024)];
        float2 x3 = src[pad(u + 1536)];
        float ang = sign * ((float)M_PI / 1024.0f) * (float)u;   // 2*pi*u/2048
        float s1, c1;
        __sincosf(ang, &s1, &c1);
        float2 w1 = make_float2(c1, s1);
        float2 w2 = cmul(w1, w1);
        float2 w3 = cmul(w2, w1);
        x1 = cmul(x1, w1); x2 = cmul(x2, w2); x3 = cmul(x3, w3);
        float2 apc = cadd(x0, x2), amc = csub(x0, x2);
        float2 bpd = cadd(x1, x3), bmd = csub(x1, x3);
        float2 e = cjrot(bmd, sign);
        dst[pad(u)]        = cadd(apc, bpd);
        dst[pad(u + 512)]  = cadd(amc, e);
        dst[pad(u + 1024)] = csub(apc, bpd);
        dst[pad(u + 1536)] = csub(amc, e);
    }
}

// input staged in bufA (padded); result returned (in bufA).
__device__ __forceinline__ float2* fft2048(float2* bufA, float2* bufB,
                                           int tid, float sign) {
    radix8_stage(bufA, bufB, tid, 1, sign);
    __syncthreads();
    radix8_stage(bufB, bufA, tid, 8, sign);
    __syncthreads();
    radix8_stage(bufA, bufB, tid, 64, sign);
    __syncthreads();
    radix4_final(bufB, bufA, tid, sign);
    __syncthreads();
    return bufA;
}

// ---------------------------------------------------------------------------
// Forward rfft per row (ortho), packed output (4096 floats / row).
// ---------------------------------------------------------------------------
__global__ __launch_bounds__(NTH) void k_rfft_fwd(const float* __restrict__ x,
                                                  float* __restrict__ out) {
    __shared__ float2 bufA[FFT_LDS_SZ];
    __shared__ float2 bufB[FFT_LDS_SZ];
    const int row = blockIdx.x;
    const float* xr = x + (size_t)row * 4096;
    float* orow = out + (size_t)row * 4096;
    const int tid = threadIdx.x;

    for (int t = tid; t < 2048; t += NTH)
        bufA[pad(t)] = *(const float2*)(xr + 2 * t);
    __syncthreads();

    float2* Z = fft2048(bufA, bufB, tid, -1.0f);

    const float scale = 1.0f / 64.0f;
    for (int k = tid; k <= 2048; k += NTH) {
        float2 zk = Z[pad(k & 2047)];
        float2 zn = Z[pad((2048 - k) & 2047)];
        float Ar = 0.5f * (zk.x + zn.x), Ai = 0.5f * (zk.y - zn.y);
        float Br = 0.5f * (zk.x - zn.x), Bi = 0.5f * (zk.y + zn.y);
        float ang = -(float)M_PI * (float)k / 2048.0f;
        float s, c;
        __sincosf(ang, &s, &c);
        float wBr = c * Br - s * Bi;
        float wBi = c * Bi + s * Br;
        float Xr = (Ar + wBi) * scale;
        float Xi = (Ai - wBr) * scale;
        if (k == 0)          orow[0] = Xr;
        else if (k == 2048)  orow[1] = Xr;
        else                 *(float2*)(orow + 2 * k) = make_float2(Xr, Xi);
    }
}

// ---------------------------------------------------------------------------
// Weight preprocessing: fp32 W[a][n][i][o] -> bf16 W^T in ws: [a][n][o][i].
// ---------------------------------------------------------------------------
__global__ __launch_bounds__(NTH) void k_prep(
    const float* __restrict__ w1_re, const float* __restrict__ w1_im,
    const float* __restrict__ w2_re, const float* __restrict__ w2_im,
    ushort* __restrict__ wt) {
    int gid = blockIdx.x * NTH + threadIdx.x;   // 0 .. 294911
    if (gid >= 294912) return;
    int a   = gid / 73728;
    int rem = gid - a * 73728;
    int n   = rem / 9216;
    int r2  = rem - n * 9216;
    int o   = r2 / 96;
    int i   = r2 - o * 96;
    const float* src = (a == 0) ? w1_re : (a == 1) ? w1_im : (a == 2) ? w2_re : w2_im;
    wt[gid] = f2bf(src[(n * 96 + i) * 96 + o]);
}

// ---------------------------------------------------------------------------
// MFMA mixer v3 (proven 199 us): barrier-free, xb-only LDS, weights straight
// from global bf16 wt (L2-resident). Grid (33, 8, 16) x 256 thr (4 waves).
// ---------------------------------------------------------------------------
__global__ __launch_bounds__(NTH, 4) void k_mix3(
    float* __restrict__ io, const ushort* __restrict__ wt,
    const float* __restrict__ b1_re, const float* __restrict__ b1_im,
    const float* __restrict__ b2_re, const float* __restrict__ b2_im) {
    __shared__ __align__(16) ushort xb[2][64][104];   // 26624 B

    const int mt = blockIdx.x;
    const int n  = blockIdx.y;
    const int b  = blockIdx.z;
    const int tid  = threadIdx.x;
    const int lane = tid & 63;
    const int wv   = tid >> 6;
    const int m0 = mt * 64;
    const int mw = wv * 16;
    float* base = io + ((size_t)b * 768 + (size_t)n * 96) * 4096;

    // ---- per-wave stage of own 16-mode stripe (no barrier needed)
    {
        const int mm = lane & 15;          // mode within stripe
        const int m  = m0 + mw + mm;
        const int i0 = lane >> 4;          // starting channel 0..3
        for (int i = i0; i < 96; i += 4) {
            const float* row = base + (size_t)i * 4096;
            float re = 0.f, im = 0.f;
            if (m == 0)          { re = row[0]; }
            else if (m == 2048)  { re = row[1]; }
            else if (m < 2048)   { float2 v = *(const float2*)(row + 2 * m); re = v.x; im = v.y; }
            xb[0][mw + mm][i] = f2bf(re);
            xb[1][mw + mm][i] = f2bf(im);
        }
    }

    const int lc = lane & 15;
    const int kl = 8 * (lane >> 4);
    const int mrow = mw + lc;
    const ushort* wn  = wt + (size_t)n * 9216;        // w1_re^T; +73728 per plane
    const ushort* wn2 = wn + 2 * 73728;               // w2_re^T

    float b1r[6], b1i[6];
#pragma unroll
    for (int nt = 0; nt < 6; ++nt) {
        b1r[nt] = b1_re[n * 96 + nt * 16 + lc];
        b1i[nt] = b1_im[n * 96 + nt * 16 + lc];
    }

    f32x4 accR[6], accI[6];
    const f32x4 zero = {0.f, 0.f, 0.f, 0.f};
#pragma unroll
    for (int nt = 0; nt < 6; ++nt) { accR[nt] = zero; accI[nt] = zero; }

    // ---- layer 1 (weight frags straight from global; all L2 hits)
#pragma unroll
    for (int kk = 0; kk < 3; ++kk) {
        const int k0 = kk * 32 + kl;
        short8 ar = *(const short8*)&xb[0][mrow][k0];
        short8 ai = *(const short8*)&xb[1][mrow][k0];
        short8 nai;
#pragma unroll
        for (int j = 0; j < 8; ++j) nai[j] = ai[j] ^ (short)0x8000;
#pragma unroll
        for (int nt = 0; nt < 6; ++nt) {
            const ushort* wp = wn + (nt * 16 + lc) * 96 + k0;
            short8 br = *(const short8*)(wp);            // w1_re^T
            short8 bi = *(const short8*)(wp + 73728);    // w1_im^T
            accR[nt] = __builtin_amdgcn_mfma_f32_16x16x32_bf16(ar,  br, accR[nt], 0, 0, 0);
            accR[nt] = __builtin_amdgcn_mfma_f32_16x16x32_bf16(nai, bi, accR[nt], 0, 0, 0);
            accI[nt] = __builtin_amdgcn_mfma_f32_16x16x32_bf16(ar,  bi, accI[nt], 0, 0, 0);
            accI[nt] = __builtin_amdgcn_mfma_f32_16x16x32_bf16(ai,  br, accI[nt], 0, 0, 0);
        }
    }
    // crelu -> h into own stripe (same-wave LDS dependency only)
#pragma unroll
    for (int nt = 0; nt < 6; ++nt) {
#pragma unroll
        for (int q = 0; q < 4; ++q) {
            int m = mw + 4 * (lane >> 4) + q;
            xb[0][m][nt * 16 + lc] = f2bf(fmaxf(accR[nt][q] + b1r[nt], 0.f));
            xb[1][m][nt * 16 + lc] = f2bf(fmaxf(accI[nt][q] + b1i[nt], 0.f));
        }
    }

    // ---- layer 2
#pragma unroll
    for (int nt = 0; nt < 6; ++nt) { accR[nt] = zero; accI[nt] = zero; }
#pragma unroll
    for (int kk = 0; kk < 3; ++kk) {
        const int k0 = kk * 32 + kl;
        short8 ar = *(const short8*)&xb[0][mrow][k0];
        short8 ai = *(const short8*)&xb[1][mrow][k0];
        short8 nai;
#pragma unroll
        for (int j = 0; j < 8; ++j) nai[j] = ai[j] ^ (short)0x8000;
#pragma unroll
        for (int nt = 0; nt < 6; ++nt) {
            const ushort* wp = wn2 + (nt * 16 + lc) * 96 + k0;
            short8 br = *(const short8*)(wp);            // w2_re^T
            short8 bi = *(const short8*)(wp + 73728);    // w2_im^T
            accR[nt] = __builtin_amdgcn_mfma_f32_16x16x32_bf16(ar,  br, accR[nt], 0, 0, 0);
            accR[nt] = __builtin_amdgcn_mfma_f32_16x16x32_bf16(nai, bi, accR[nt], 0, 0, 0);
            accI[nt] = __builtin_amdgcn_mfma_f32_16x16x32_bf16(ar,  bi, accI[nt], 0, 0, 0);
            accI[nt] = __builtin_amdgcn_mfma_f32_16x16x32_bf16(ai,  br, accI[nt], 0, 0, 0);
        }
    }

    // softshrink + in-place packed store (b2 biases loaded late to cut live regs)
    float b2r[6], b2i[6];
#pragma unroll
    for (int nt = 0; nt < 6; ++nt) {
        b2r[nt] = b2_re[n * 96 + nt * 16 + lc];
        b2i[nt] = b2_im[n * 96 + nt * 16 + lc];
    }
#pragma unroll
    for (int nt = 0; nt < 6; ++nt) {
#pragma unroll
        for (int q = 0; q < 4; ++q) {
            int m = m0 + mw + 4 * (lane >> 4) + q;
            float vr = accR[nt][q] + b2r[nt];
            float vi = accI[nt][q] + b2i[nt];
            float sr = copysignf(fmaxf(fabsf(vr) - LAM, 0.f), vr);
            float si = copysignf(fmaxf(fabsf(vi) - LAM, 0.f), vi);
            float* row = base + (size_t)(nt * 16 + lc) * 4096;
            if (m == 0)          row[0] = sr;
            else if (m == 2048)  row[1] = sr;
            else if (m < 2048)   *(float2*)(row + 2 * m) = make_float2(sr, si);
        }
    }
}

// ---------------------------------------------------------------------------
// Fallback mixer (no ws dependency).
// ---------------------------------------------------------------------------
__global__ __launch_bounds__(NTH) void k_mix_fallback(
    float* __restrict__ io,
    const float* __restrict__ w1_re, const float* __restrict__ w1_im,
    const float* __restrict__ w2_re, const float* __restrict__ w2_im,
    const float* __restrict__ b1_re, const float* __restrict__ b1_im,
    const float* __restrict__ b2_re, const float* __restrict__ b2_im) {
    __shared__ __align__(16) ushort xb[2][64][96];
    __shared__ __align__(16) ushort wb[2][96][104];

    const int mt = blockIdx.x;
    const int n  = blockIdx.y;
    const int b  = blockIdx.z;
    const int tid = threadIdx.x;
    const int lane = tid & 63;
    const int wv   = tid >> 6;
    const int m0 = mt * 64;
    float* base = io + ((size_t)b * 768 + (size_t)n * 96) * 4096;

    for (int idx = tid; idx < 96 * 64; idx += NTH) {
        int i = idx >> 6, mm = idx & 63;
        int m = m0 + mm;
        const float* row = base + (size_t)i * 4096;
        float re = 0.f, im = 0.f;
        if (m == 0) { re = row[0]; }
        else if (m == 2048) { re = row[1]; }
        else if (m < 2048) { float2 v = *(const float2*)(row + 2 * m); re = v.x; im = v.y; }
        xb[0][mm][i] = f2bf(re);
        xb[1][mm][i] = f2bf(im);
    }
    const float* W1r = w1_re + (size_t)n * 9216;
    const float* W1i = w1_im + (size_t)n * 9216;
    for (int idx = tid; idx < 9216; idx += NTH) {
        int i = idx / 96, o = idx - i * 96;
        wb[0][o][i] = f2bf(W1r[idx]);
        wb[1][o][i] = f2bf(W1i[idx]);
    }
    const int lc = lane & 15;
    float b1r[6], b1i[6], b2r[6], b2i[6];
#pragma unroll
    for (int nt = 0; nt < 6; ++nt) {
        b1r[nt] = b1_re[n * 96 + nt * 16 + lc];
        b1i[nt] = b1_im[n * 96 + nt * 16 + lc];
        b2r[nt] = b2_re[n * 96 + nt * 16 + lc];
        b2i[nt] = b2_im[n * 96 + nt * 16 + lc];
    }
    __syncthreads();

    const int mw = wv * 16;
    const int klr = 8 * (lane >> 4);
    const int mrow = mw + lc;

    f32x4 accR[6], accI[6];
    const f32x4 zero = {0.f, 0.f, 0.f, 0.f};
#pragma unroll
    for (int nt = 0; nt < 6; ++nt) { accR[nt] = zero; accI[nt] = zero; }

#pragma unroll
    for (int kk = 0; kk < 3; ++kk) {
        int k0 = kk * 32 + klr;
        short8 ar = *(const short8*)&xb[0][mrow][k0];
        short8 ai = *(const short8*)&xb[1][mrow][k0];
        short8 nai;
#pragma unroll
        for (int j = 0; j < 8; ++j) nai[j] = ai[j] ^ (short)0x8000;
#pragma unroll
        for (int nt = 0; nt < 6; ++nt) {
            short8 br = *(const short8*)&wb[0][nt * 16 + lc][k0];
            short8 bi = *(const short8*)&wb[1][nt * 16 + lc][k0];
            accR[nt] = __builtin_amdgcn_mfma_f32_16x16x32_bf16(ar,  br, accR[nt], 0, 0, 0);
            accR[nt] = __builtin_amdgcn_mfma_f32_16x16x32_bf16(nai, bi, accR[nt], 0, 0, 0);
            accI[nt] = __builtin_amdgcn_mfma_f32_16x16x32_bf16(ar,  bi, accI[nt], 0, 0, 0);
            accI[nt] = __builtin_amdgcn_mfma_f32_16x16x32_bf16(ai,  br, accI[nt], 0, 0, 0);
        }
    }
#pragma unroll
    for (int nt = 0; nt < 6; ++nt) {
#pragma unroll
        for (int q = 0; q < 4; ++q) {
            int m = mw + 4 * (lane >> 4) + q;
            float hr = fmaxf(accR[nt][q] + b1r[nt], 0.f);
            float hi = fmaxf(accI[nt][q] + b1i[nt], 0.f);
            xb[0][m][nt * 16 + lc] = f2bf(hr);
            xb[1][m][nt * 16 + lc] = f2bf(hi);
        }
    }
    __syncthreads();

    const float* W2r = w2_re + (size_t)n * 9216;
    const float* W2i = w2_im + (size_t)n * 9216;
    for (int idx = tid; idx < 9216; idx += NTH) {
        int i = idx / 96, o = idx - i * 96;
        wb[0][o][i] = f2bf(W2r[idx]);
        wb[1][o][i] = f2bf(W2i[idx]);
    }
    __syncthreads();

#pragma unroll
    for (int nt = 0; nt < 6; ++nt) { accR[nt] = zero; accI[nt] = zero; }
#pragma unroll
    for (int kk = 0; kk < 3; ++kk) {
        int k0 = kk * 32 + klr;
        short8 ar = *(const short8*)&xb[0][mrow][k0];
        short8 ai = *(const short8*)&xb[1][mrow][k0];
        short8 nai;
#pragma unroll
        for (int j = 0; j < 8; ++j) nai[j] = ai[j] ^ (short)0x8000;
#pragma unroll
        for (int nt = 0; nt < 6; ++nt) {
            short8 br = *(const short8*)&wb[0][nt * 16 + lc][k0];
            short8 bi = *(const short8*)&wb[1][nt * 16 + lc][k0];
            accR[nt] = __builtin_amdgcn_mfma_f32_16x16x32_bf16(ar,  br, accR[nt], 0, 0, 0);
            accR[nt] = __builtin_amdgcn_mfma_f32_16x16x32_bf16(nai, bi, accR[nt], 0, 0, 0);
            accI[nt] = __builtin_amdgcn_mfma_f32_16x16x32_bf16(ar,  bi, accI[nt], 0, 0, 0);
            accI[nt] = __builtin_amdgcn_mfma_f32_16x16x32_bf16(ai,  br, accI[nt], 0, 0, 0);
        }
    }
#pragma unroll
    for (int nt = 0; nt < 6; ++nt) {
#pragma unroll
        for (int q = 0; q < 4; ++q) {
            int m = m0 + mw + 4 * (lane >> 4) + q;
            float vr = accR[nt][q] + b2r[nt];
            float vi = accI[nt][q] + b2i[nt];
            float sr = copysignf(fmaxf(fabsf(vr) - LAM, 0.f), vr);
            float si = copysignf(fmaxf(fabsf(vi) - LAM, 0.f), vi);
            float* row = base + (size_t)(nt * 16 + lc) * 4096;
            if (m == 0)          row[0] = sr;
            else if (m == 2048)  row[1] = sr;
            else if (m < 2048)   *(float2*)(row + 2 * m) = make_float2(sr, si);
        }
    }
}

// ---------------------------------------------------------------------------
// Inverse rfft per row (ortho) + residual add, in-place on packed spectrum.
// ---------------------------------------------------------------------------
__global__ __launch_bounds__(NTH) void k_irfft_add(const float* __restrict__ x,
                                                   float* __restrict__ io) {
    __shared__ float2 bufA[FFT_LDS_SZ];
    __shared__ float2 bufB[FFT_LDS_SZ];
    const int row = blockIdx.x;
    const float* xr = x + (size_t)row * 4096;
    float* orow = io + (size_t)row * 4096;
    const int tid = threadIdx.x;
    const float scale = 1.0f / 32.0f;

    for (int k = tid; k < 2048; k += NTH) {
        float Xr, Xi, Yr, Yi;
        if (k == 0) {
            Xr = orow[0]; Xi = 0.f; Yr = orow[1]; Yi = 0.f;
        } else {
            float2 a  = *(const float2*)(orow + 2 * k);
            float2 bq = *(const float2*)(orow + 2 * (2048 - k));
            Xr = a.x; Xi = a.y; Yr = bq.x; Yi = bq.y;
        }
        float Fer = 0.5f * (Xr + Yr), Fei = 0.5f * (Xi - Yi);
        float Dr  = 0.5f * (Xr - Yr), Di  = 0.5f * (Xi + Yi);
        float ang = (float)M_PI * (float)k / 2048.0f;
        float s, c;
        __sincosf(ang, &s, &c);
        float For = c * Dr - s * Di;
        float Foi = c * Di + s * Dr;
        bufA[pad(k)] = make_float2((Fer - Foi) * scale, (Fei + For) * scale);
    }
    __syncthreads();

    float2* Zt = fft2048(bufA, bufB, tid, 1.0f);

    for (int t = tid; t < 2048; t += NTH) {
        float2 z  = Zt[pad(t)];
        float2 xv = *(const float2*)(xr + 2 * t);
        *(float2*)(orow + 2 * t) = make_float2(z.x + xv.x, z.y + xv.y);
    }
}

// ---------------------------------------------------------------------------
extern "C" void kernel_launch(void* const* d_in, const int* in_sizes, int n_in,
                              void* d_out, int out_size, void* d_ws, size_t ws_size,
                              hipStream_t stream) {
    const float* x     = (const float*)d_in[0];
    const float* w1_re = (const float*)d_in[1];
    const float* w1_im = (const float*)d_in[2];
    const float* w2_re = (const float*)d_in[3];
    const float* w2_im = (const float*)d_in[4];
    const float* b1_re = (const float*)d_in[5];
    const float* b1_im = (const float*)d_in[6];
    const float* b2_re = (const float*)d_in[7];
    const float* b2_im = (const float*)d_in[8];
    float* out = (float*)d_out;

    k_rfft_fwd<<<12288, NTH, 0, stream>>>(x, out);
    if (ws_size >= (size_t)WS_WT_BYTES) {
        ushort* wt = (ushort*)d_ws;
        k_prep<<<(294912 + NTH - 1) / NTH, NTH, 0, stream>>>(w1_re, w1_im, w2_re, w2_im, wt);
        k_mix3<<<dim3(33, 8, 16), NTH, 0, stream>>>(out, wt, b1_re, b1_im, b2_re, b2_im);
    } else {
        k_mix_fallback<<<dim3(33, 8, 16), NTH, 0, stream>>>(out, w1_re, w1_im, w2_re, w2_im,
                                                            b1_re, b1_im, b2_re, b2_im);
    }
    k_irfft_add<<<12288, NTH, 0, stream>>>(x, out);
}

// Round 5
// 373.178 us; speedup vs baseline: 1.2484x; 1.1453x over previous
//
#include <hip/hip_runtime.h>
#include <math.h>

#define NTH 256
#define LAM 0.01f
#define WS_WT_BYTES 589824   // 4 planes * 8 blocks * 96*96 * 2B (bf16 W^T)

typedef __attribute__((ext_vector_type(8))) short short8;
typedef __attribute__((ext_vector_type(8))) unsigned short ushort8;
typedef __attribute__((ext_vector_type(4))) float f32x4;

__device__ __forceinline__ ushort f2bf(float f) {
    union { float f; unsigned u; } c; c.f = f;
    unsigned u = c.u;
    u += 0x7fffu + ((u >> 16) & 1u);   // round-to-nearest-even
    return (ushort)(u >> 16);
}

// LDS index padding: one extra float2 every 8 -> radix-8's stride-8 scatter
// becomes stride-9 (16 distinct bank-pairs = minimum phases for b64).
__device__ __forceinline__ int pad(int i) { return i + (i >> 3); }
#define FFT_LDS_SZ 2304   // pad(2047)=2302, round up

// ---- complex helpers -------------------------------------------------------
__device__ __forceinline__ float2 cadd(float2 a, float2 b) { return make_float2(a.x + b.x, a.y + b.y); }
__device__ __forceinline__ float2 csub(float2 a, float2 b) { return make_float2(a.x - b.x, a.y - b.y); }
__device__ __forceinline__ float2 cmul(float2 a, float2 b) { return make_float2(a.x * b.x - a.y * b.y, a.x * b.y + a.y * b.x); }
__device__ __forceinline__ float2 cjrot(float2 a, float sign) { return make_float2(-sign * a.y, sign * a.x); } // sign*i*a

// ---------------------------------------------------------------------------
// Stockham mixed-radix FFT of length 2048: 3 radix-8 stages + 1 radix-4.
// ---------------------------------------------------------------------------
__device__ __forceinline__ void radix8_stage(const float2* __restrict__ src,
                                             float2* __restrict__ dst,
                                             int tid, int Ns, float sign) {
    const int u = tid;                       // 256 butterflies, 256 threads
    const int r = u & (Ns - 1);
    float2 t0 = src[pad(u)];
    float2 t1 = src[pad(u + 256)];
    float2 t2 = src[pad(u + 512)];
    float2 t3 = src[pad(u + 768)];
    float2 t4 = src[pad(u + 1024)];
    float2 t5 = src[pad(u + 1280)];
    float2 t6 = src[pad(u + 1536)];
    float2 t7 = src[pad(u + 1792)];
    if (Ns > 1) {
        float ang = sign * ((float)M_PI / (4.0f * (float)Ns)) * (float)r;  // 2*pi*r/(8*Ns)
        float s1, c1;
        __sincosf(ang, &s1, &c1);
        float2 w1 = make_float2(c1, s1);
        float2 w2 = cmul(w1, w1);
        float2 w3 = cmul(w2, w1);
        float2 w4 = cmul(w2, w2);
        float2 w5 = cmul(w4, w1);
        float2 w6 = cmul(w4, w2);
        float2 w7 = cmul(w4, w3);
        t1 = cmul(t1, w1); t2 = cmul(t2, w2); t3 = cmul(t3, w3);
        t4 = cmul(t4, w4); t5 = cmul(t5, w5); t6 = cmul(t6, w6);
        t7 = cmul(t7, w7);
    }
    // even 4-pt DFT on (t0,t2,t4,t6)
    float2 apc = cadd(t0, t4), amc = csub(t0, t4);
    float2 bpd = cadd(t2, t6), bmd = csub(t2, t6);
    float2 e0 = cadd(apc, bpd), e2 = csub(apc, bpd);
    float2 jb = cjrot(bmd, sign);
    float2 e1 = cadd(amc, jb), e3 = csub(amc, jb);
    // odd 4-pt DFT on (t1,t3,t5,t7)
    float2 apc2 = cadd(t1, t5), amc2 = csub(t1, t5);
    float2 bpd2 = cadd(t3, t7), bmd2 = csub(t3, t7);
    float2 o0 = cadd(apc2, bpd2), o2 = csub(apc2, bpd2);
    float2 jb2 = cjrot(bmd2, sign);
    float2 o1 = cadd(amc2, jb2), o3 = csub(amc2, jb2);
    // twiddle odd results by W8^q
    const float H = 0.70710678118654752f;
    o1 = cmul(o1, make_float2(H, sign * H));
    o2 = cjrot(o2, sign);
    o3 = cmul(o3, make_float2(-H, sign * H));
    const int d = ((u - r) << 3) + r;
    dst[pad(d)]          = cadd(e0, o0);
    dst[pad(d + Ns)]     = cadd(e1, o1);
    dst[pad(d + 2 * Ns)] = cadd(e2, o2);
    dst[pad(d + 3 * Ns)] = cadd(e3, o3);
    dst[pad(d + 4 * Ns)] = csub(e0, o0);
    dst[pad(d + 5 * Ns)] = csub(e1, o1);
    dst[pad(d + 6 * Ns)] = csub(e2, o2);
    dst[pad(d + 7 * Ns)] = csub(e3, o3);
}

__device__ __forceinline__ void radix4_final(const float2* __restrict__ src,
                                             float2* __restrict__ dst,
                                             int tid, float sign) {
    for (int u = tid; u < 512; u += NTH) {
        float2 x0 = src[pad(u)];
        float2 x1 = src[pad(u + 512)];
        float2 x2 = src[pad(u + 1024)];
        float2 x3 = src[pad(u + 1536)];
        float ang = sign * ((float)M_PI / 1024.0f) * (float)u;   // 2*pi*u/2048
        float s1, c1;
        __sincosf(ang, &s1, &c1);
        float2 w1 = make_float2(c1, s1);
        float2 w2 = cmul(w1, w1);
        float2 w3 = cmul(w2, w1);
        x1 = cmul(x1, w1); x2 = cmul(x2, w2); x3 = cmul(x3, w3);
        float2 apc = cadd(x0, x2), amc = csub(x0, x2);
        float2 bpd = cadd(x1, x3), bmd = csub(x1, x3);
        float2 e = cjrot(bmd, sign);
        dst[pad(u)]        = cadd(apc, bpd);
        dst[pad(u + 512)]  = cadd(amc, e);
        dst[pad(u + 1024)] = csub(apc, bpd);
        dst[pad(u + 1536)] = csub(amc, e);
    }
}

__device__ __forceinline__ float2* fft2048(float2* bufA, float2* bufB,
                                           int tid, float sign) {
    radix8_stage(bufA, bufB, tid, 1, sign);
    __syncthreads();
    radix8_stage(bufB, bufA, tid, 8, sign);
    __syncthreads();
    radix8_stage(bufA, bufB, tid, 64, sign);
    __syncthreads();
    radix4_final(bufB, bufA, tid, sign);
    __syncthreads();
    return bufA;
}

// ---------------------------------------------------------------------------
// Forward rfft per row (ortho), packed output (4096 floats / row).
// ---------------------------------------------------------------------------
__global__ __launch_bounds__(NTH) void k_rfft_fwd(const float* __restrict__ x,
                                                  float* __restrict__ out) {
    __shared__ float2 bufA[FFT_LDS_SZ];
    __shared__ float2 bufB[FFT_LDS_SZ];
    const int row = blockIdx.x;
    const float* xr = x + (size_t)row * 4096;
    float* orow = out + (size_t)row * 4096;
    const int tid = threadIdx.x;

    for (int t = tid; t < 2048; t += NTH)
        bufA[pad(t)] = *(const float2*)(xr + 2 * t);
    __syncthreads();

    float2* Z = fft2048(bufA, bufB, tid, -1.0f);

    const float scale = 1.0f / 64.0f;
    for (int k = tid; k <= 2048; k += NTH) {
        float2 zk = Z[pad(k & 2047)];
        float2 zn = Z[pad((2048 - k) & 2047)];
        float Ar = 0.5f * (zk.x + zn.x), Ai = 0.5f * (zk.y - zn.y);
        float Br = 0.5f * (zk.x - zn.x), Bi = 0.5f * (zk.y + zn.y);
        float ang = -(float)M_PI * (float)k / 2048.0f;
        float s, c;
        __sincosf(ang, &s, &c);
        float wBr = c * Br - s * Bi;
        float wBi = c * Bi + s * Br;
        float Xr = (Ar + wBi) * scale;
        float Xi = (Ai - wBr) * scale;
        if (k == 0)          orow[0] = Xr;
        else if (k == 2048)  orow[1] = Xr;
        else                 *(float2*)(orow + 2 * k) = make_float2(Xr, Xi);
    }
}

// ---------------------------------------------------------------------------
// Weight preprocessing: fp32 W[a][n][i][o] -> bf16 W^T in ws: [a][n][o][i].
// ---------------------------------------------------------------------------
__global__ __launch_bounds__(NTH) void k_prep(
    const float* __restrict__ w1_re, const float* __restrict__ w1_im,
    const float* __restrict__ w2_re, const float* __restrict__ w2_im,
    ushort* __restrict__ wt) {
    int gid = blockIdx.x * NTH + threadIdx.x;   // 0 .. 294911
    if (gid >= 294912) return;
    int a   = gid / 73728;
    int rem = gid - a * 73728;
    int n   = rem / 9216;
    int r2  = rem - n * 9216;
    int o   = r2 / 96;
    int i   = r2 - o * 96;
    const float* src = (a == 0) ? w1_re : (a == 1) ? w1_im : (a == 2) ? w2_re : w2_im;
    wt[gid] = f2bf(src[(n * 96 + i) * 96 + o]);
}

// ---------------------------------------------------------------------------
// MFMA mixer v5: barrier-free (k_mix3 structure) + explicit MLP batching.
//  - __launch_bounds__(NTH,3): let compiler use ~170 VGPR (was capped-by-
//    heuristic at 64 = acc+frags only -> every load's latency was exposed).
//  - stage loads batched 12-deep into registers before f2bf/LDS-write.
//  - all 12 weight fragments of a kk-step preloaded before its 24 MFMAs.
//  - epilogue: 4 consecutive modes packed into two float4 stores per (nt).
// Grid (33, 8, 16) x 256 thr (4 waves).
// ---------------------------------------------------------------------------
__global__ __launch_bounds__(NTH, 3) void k_mix5(
    float* __restrict__ io, const ushort* __restrict__ wt,
    const float* __restrict__ b1_re, const float* __restrict__ b1_im,
    const float* __restrict__ b2_re, const float* __restrict__ b2_im) {
    __shared__ __align__(16) ushort xb[2][64][104];   // 26624 B

    const int mt = blockIdx.x;
    const int n  = blockIdx.y;
    const int b  = blockIdx.z;
    const int tid  = threadIdx.x;
    const int lane = tid & 63;
    const int wv   = tid >> 6;
    const int m0 = mt * 64;
    const int mw = wv * 16;
    float* base = io + ((size_t)b * 768 + (size_t)n * 96) * 4096;

    const int lc = lane & 15;
    const int hi = lane >> 4;

    // ---- stage own 16-mode stripe; batched loads (fast path: interior modes)
    {
        const int m = m0 + mw + lc;            // this lane's mode
        if (m >= 1 && m < 2048) {
            const float* src0 = base + 2 * m;
#pragma unroll
            for (int half = 0; half < 2; ++half) {
                float2 v[12];
#pragma unroll
                for (int t = 0; t < 12; ++t) {
                    const int i = hi + 4 * (12 * half + t);
                    v[t] = *(const float2*)(src0 + (size_t)i * 4096);
                }
#pragma unroll
                for (int t = 0; t < 12; ++t) {
                    const int i = hi + 4 * (12 * half + t);
                    xb[0][mw + lc][i] = f2bf(v[t].x);
                    xb[1][mw + lc][i] = f2bf(v[t].y);
                }
            }
        } else {
            for (int i = hi; i < 96; i += 4) {
                const float* row = base + (size_t)i * 4096;
                float re = 0.f;
                if (m == 0)          re = row[0];
                else if (m == 2048)  re = row[1];
                xb[0][mw + lc][i] = f2bf(re);
                xb[1][mw + lc][i] = 0;
            }
        }
    }

    const int kl = 8 * hi;
    const int mrow = mw + lc;
    const ushort* wn  = wt + (size_t)n * 9216;        // w1_re^T; +73728 per plane
    const ushort* wn2 = wn + 2 * 73728;               // w2_re^T

    float b1r[6], b1i[6];
#pragma unroll
    for (int nt = 0; nt < 6; ++nt) {
        b1r[nt] = b1_re[n * 96 + nt * 16 + lc];
        b1i[nt] = b1_im[n * 96 + nt * 16 + lc];
    }

    f32x4 accR[6], accI[6];
    const f32x4 zero = {0.f, 0.f, 0.f, 0.f};
#pragma unroll
    for (int nt = 0; nt < 6; ++nt) { accR[nt] = zero; accI[nt] = zero; }

    // ---- layer 1: preload 12 weight frags per kk, then 24 MFMAs
#pragma unroll
    for (int kk = 0; kk < 3; ++kk) {
        const int k0 = kk * 32 + kl;
        short8 wr[6], wi[6];
#pragma unroll
        for (int nt = 0; nt < 6; ++nt) {
            const ushort* wp = wn + (nt * 16 + lc) * 96 + k0;
            wr[nt] = *(const short8*)(wp);
            wi[nt] = *(const short8*)(wp + 73728);
        }
        short8 ar = *(const short8*)&xb[0][mrow][k0];
        short8 ai = *(const short8*)&xb[1][mrow][k0];
        short8 nai;
#pragma unroll
        for (int j = 0; j < 8; ++j) nai[j] = ai[j] ^ (short)0x8000;
#pragma unroll
        for (int nt = 0; nt < 6; ++nt) {
            accR[nt] = __builtin_amdgcn_mfma_f32_16x16x32_bf16(ar,  wr[nt], accR[nt], 0, 0, 0);
            accR[nt] = __builtin_amdgcn_mfma_f32_16x16x32_bf16(nai, wi[nt], accR[nt], 0, 0, 0);
            accI[nt] = __builtin_amdgcn_mfma_f32_16x16x32_bf16(ar,  wi[nt], accI[nt], 0, 0, 0);
            accI[nt] = __builtin_amdgcn_mfma_f32_16x16x32_bf16(ai,  wr[nt], accI[nt], 0, 0, 0);
        }
    }
    // crelu -> h into own stripe (same-wave LDS dependency only)
#pragma unroll
    for (int nt = 0; nt < 6; ++nt) {
#pragma unroll
        for (int q = 0; q < 4; ++q) {
            int m = mw + 4 * hi + q;
            xb[0][m][nt * 16 + lc] = f2bf(fmaxf(accR[nt][q] + b1r[nt], 0.f));
            xb[1][m][nt * 16 + lc] = f2bf(fmaxf(accI[nt][q] + b1i[nt], 0.f));
        }
    }

    // ---- layer 2
#pragma unroll
    for (int nt = 0; nt < 6; ++nt) { accR[nt] = zero; accI[nt] = zero; }
#pragma unroll
    for (int kk = 0; kk < 3; ++kk) {
        const int k0 = kk * 32 + kl;
        short8 wr[6], wi[6];
#pragma unroll
        for (int nt = 0; nt < 6; ++nt) {
            const ushort* wp = wn2 + (nt * 16 + lc) * 96 + k0;
            wr[nt] = *(const short8*)(wp);
            wi[nt] = *(const short8*)(wp + 73728);
        }
        short8 ar = *(const short8*)&xb[0][mrow][k0];
        short8 ai = *(const short8*)&xb[1][mrow][k0];
        short8 nai;
#pragma unroll
        for (int j = 0; j < 8; ++j) nai[j] = ai[j] ^ (short)0x8000;
#pragma unroll
        for (int nt = 0; nt < 6; ++nt) {
            accR[nt] = __builtin_amdgcn_mfma_f32_16x16x32_bf16(ar,  wr[nt], accR[nt], 0, 0, 0);
            accR[nt] = __builtin_amdgcn_mfma_f32_16x16x32_bf16(nai, wi[nt], accR[nt], 0, 0, 0);
            accI[nt] = __builtin_amdgcn_mfma_f32_16x16x32_bf16(ar,  wi[nt], accI[nt], 0, 0, 0);
            accI[nt] = __builtin_amdgcn_mfma_f32_16x16x32_bf16(ai,  wr[nt], accI[nt], 0, 0, 0);
        }
    }

    // ---- softshrink + packed store: 4 consecutive modes -> two float4 stores
    float b2r[6], b2i[6];
#pragma unroll
    for (int nt = 0; nt < 6; ++nt) {
        b2r[nt] = b2_re[n * 96 + nt * 16 + lc];
        b2i[nt] = b2_im[n * 96 + nt * 16 + lc];
    }
    const int mq = m0 + mw + 4 * hi;          // first of this lane's 4 modes
#pragma unroll
    for (int nt = 0; nt < 6; ++nt) {
        float sr[4], si[4];
#pragma unroll
        for (int q = 0; q < 4; ++q) {
            float vr = accR[nt][q] + b2r[nt];
            float vi = accI[nt][q] + b2i[nt];
            sr[q] = copysignf(fmaxf(fabsf(vr) - LAM, 0.f), vr);
            si[q] = copysignf(fmaxf(fabsf(vi) - LAM, 0.f), vi);
        }
        float* row = base + (size_t)(nt * 16 + lc) * 4096;
        if (mq >= 1 && mq + 3 < 2048) {
            f32x4 lo = {sr[0], si[0], sr[1], si[1]};
            f32x4 hv = {sr[2], si[2], sr[3], si[3]};
            *(f32x4*)(row + 2 * mq)     = lo;
            *(f32x4*)(row + 2 * mq + 4) = hv;
        } else {
#pragma unroll
            for (int q = 0; q < 4; ++q) {
                int m = mq + q;
                if (m == 0)          row[0] = sr[q];
                else if (m == 2048)  row[1] = sr[q];
                else if (m < 2048)   *(float2*)(row + 2 * m) = make_float2(sr[q], si[q]);
            }
        }
    }
}

// ---------------------------------------------------------------------------
// Fallback mixer (no ws dependency).
// ---------------------------------------------------------------------------
__global__ __launch_bounds__(NTH) void k_mix_fallback(
    float* __restrict__ io,
    const float* __restrict__ w1_re, const float* __restrict__ w1_im,
    const float* __restrict__ w2_re, const float* __restrict__ w2_im,
    const float* __restrict__ b1_re, const float* __restrict__ b1_im,
    const float* __restrict__ b2_re, const float* __restrict__ b2_im) {
    __shared__ __align__(16) ushort xb[2][64][96];
    __shared__ __align__(16) ushort wb[2][96][104];

    const int mt = blockIdx.x;
    const int n  = blockIdx.y;
    const int b  = blockIdx.z;
    const int tid = threadIdx.x;
    const int lane = tid & 63;
    const int wv   = tid >> 6;
    const int m0 = mt * 64;
    float* base = io + ((size_t)b * 768 + (size_t)n * 96) * 4096;

    for (int idx = tid; idx < 96 * 64; idx += NTH) {
        int i = idx >> 6, mm = idx & 63;
        int m = m0 + mm;
        const float* row = base + (size_t)i * 4096;
        float re = 0.f, im = 0.f;
        if (m == 0) { re = row[0]; }
        else if (m == 2048) { re = row[1]; }
        else if (m < 2048) { float2 v = *(const float2*)(row + 2 * m); re = v.x; im = v.y; }
        xb[0][mm][i] = f2bf(re);
        xb[1][mm][i] = f2bf(im);
    }
    const float* W1r = w1_re + (size_t)n * 9216;
    const float* W1i = w1_im + (size_t)n * 9216;
    for (int idx = tid; idx < 9216; idx += NTH) {
        int i = idx / 96, o = idx - i * 96;
        wb[0][o][i] = f2bf(W1r[idx]);
        wb[1][o][i] = f2bf(W1i[idx]);
    }
    const int lc = lane & 15;
    float b1r[6], b1i[6], b2r[6], b2i[6];
#pragma unroll
    for (int nt = 0; nt < 6; ++nt) {
        b1r[nt] = b1_re[n * 96 + nt * 16 + lc];
        b1i[nt] = b1_im[n * 96 + nt * 16 + lc];
        b2r[nt] = b2_re[n * 96 + nt * 16 + lc];
        b2i[nt] = b2_im[n * 96 + nt * 16 + lc];
    }
    __syncthreads();

    const int mw = wv * 16;
    const int klr = 8 * (lane >> 4);
    const int mrow = mw + lc;

    f32x4 accR[6], accI[6];
    const f32x4 zero = {0.f, 0.f, 0.f, 0.f};
#pragma unroll
    for (int nt = 0; nt < 6; ++nt) { accR[nt] = zero; accI[nt] = zero; }

#pragma unroll
    for (int kk = 0; kk < 3; ++kk) {
        int k0 = kk * 32 + klr;
        short8 ar = *(const short8*)&xb[0][mrow][k0];
        short8 ai = *(const short8*)&xb[1][mrow][k0];
        short8 nai;
#pragma unroll
        for (int j = 0; j < 8; ++j) nai[j] = ai[j] ^ (short)0x8000;
#pragma unroll
        for (int nt = 0; nt < 6; ++nt) {
            short8 br = *(const short8*)&wb[0][nt * 16 + lc][k0];
            short8 bi = *(const short8*)&wb[1][nt * 16 + lc][k0];
            accR[nt] = __builtin_amdgcn_mfma_f32_16x16x32_bf16(ar,  br, accR[nt], 0, 0, 0);
            accR[nt] = __builtin_amdgcn_mfma_f32_16x16x32_bf16(nai, bi, accR[nt], 0, 0, 0);
            accI[nt] = __builtin_amdgcn_mfma_f32_16x16x32_bf16(ar,  bi, accI[nt], 0, 0, 0);
            accI[nt] = __builtin_amdgcn_mfma_f32_16x16x32_bf16(ai,  br, accI[nt], 0, 0, 0);
        }
    }
#pragma unroll
    for (int nt = 0; nt < 6; ++nt) {
#pragma unroll
        for (int q = 0; q < 4; ++q) {
            int m = mw + 4 * (lane >> 4) + q;
            float hr = fmaxf(accR[nt][q] + b1r[nt], 0.f);
            float hi = fmaxf(accI[nt][q] + b1i[nt], 0.f);
            xb[0][m][nt * 16 + lc] = f2bf(hr);
            xb[1][m][nt * 16 + lc] = f2bf(hi);
        }
    }
    __syncthreads();

    const float* W2r = w2_re + (size_t)n * 9216;
    const float* W2i = w2_im + (size_t)n * 9216;
    for (int idx = tid; idx < 9216; idx += NTH) {
        int i = idx / 96, o = idx - i * 96;
        wb[0][o][i] = f2bf(W2r[idx]);
        wb[1][o][i] = f2bf(W2i[idx]);
    }
    __syncthreads();

#pragma unroll
    for (int nt = 0; nt < 6; ++nt) { accR[nt] = zero; accI[nt] = zero; }
#pragma unroll
    for (int kk = 0; kk < 3; ++kk) {
        int k0 = kk * 32 + klr;
        short8 ar = *(const short8*)&xb[0][mrow][k0];
        short8 ai = *(const short8*)&xb[1][mrow][k0];
        short8 nai;
#pragma unroll
        for (int j = 0; j < 8; ++j) nai[j] = ai[j] ^ (short)0x8000;
#pragma unroll
        for (int nt = 0; nt < 6; ++nt) {
            short8 br = *(const short8*)&wb[0][nt * 16 + lc][k0];
            short8 bi = *(const short8*)&wb[1][nt * 16 + lc][k0];
            accR[nt] = __builtin_amdgcn_mfma_f32_16x16x32_bf16(ar,  br, accR[nt], 0, 0, 0);
            accR[nt] = __builtin_amdgcn_mfma_f32_16x16x32_bf16(nai, bi, accR[nt], 0, 0, 0);
            accI[nt] = __builtin_amdgcn_mfma_f32_16x16x32_bf16(ar,  bi, accI[nt], 0, 0, 0);
            accI[nt] = __builtin_amdgcn_mfma_f32_16x16x32_bf16(ai,  br, accI[nt], 0, 0, 0);
        }
    }
#pragma unroll
    for (int nt = 0; nt < 6; ++nt) {
#pragma unroll
        for (int q = 0; q < 4; ++q) {
            int m = m0 + mw + 4 * (lane >> 4) + q;
            float vr = accR[nt][q] + b2r[nt];
            float vi = accI[nt][q] + b2i[nt];
            float sr = copysignf(fmaxf(fabsf(vr) - LAM, 0.f), vr);
            float si = copysignf(fmaxf(fabsf(vi) - LAM, 0.f), vi);
            float* row = base + (size_t)(nt * 16 + lc) * 4096;
            if (m == 0)          row[0] = sr;
            else if (m == 2048)  row[1] = sr;
            else if (m < 2048)   *(float2*)(row + 2 * m) = make_float2(sr, si);
        }
    }
}

// ---------------------------------------------------------------------------
// Inverse rfft per row (ortho) + residual add, in-place on packed spectrum.
// ---------------------------------------------------------------------------
__global__ __launch_bounds__(NTH) void k_irfft_add(const float* __restrict__ x,
                                                   float* __restrict__ io) {
    __shared__ float2 bufA[FFT_LDS_SZ];
    __shared__ float2 bufB[FFT_LDS_SZ];
    const int row = blockIdx.x;
    const float* xr = x + (size_t)row * 4096;
    float* orow = io + (size_t)row * 4096;
    const int tid = threadIdx.x;
    const float scale = 1.0f / 32.0f;

    for (int k = tid; k < 2048; k += NTH) {
        float Xr, Xi, Yr, Yi;
        if (k == 0) {
            Xr = orow[0]; Xi = 0.f; Yr = orow[1]; Yi = 0.f;
        } else {
            float2 a  = *(const float2*)(orow + 2 * k);
            float2 bq = *(const float2*)(orow + 2 * (2048 - k));
            Xr = a.x; Xi = a.y; Yr = bq.x; Yi = bq.y;
        }
        float Fer = 0.5f * (Xr + Yr), Fei = 0.5f * (Xi - Yi);
        float Dr  = 0.5f * (Xr - Yr), Di  = 0.5f * (Xi + Yi);
        float ang = (float)M_PI * (float)k / 2048.0f;
        float s, c;
        __sincosf(ang, &s, &c);
        float For = c * Dr - s * Di;
        float Foi = c * Di + s * Dr;
        bufA[pad(k)] = make_float2((Fer - Foi) * scale, (Fei + For) * scale);
    }
    __syncthreads();

    float2* Zt = fft2048(bufA, bufB, tid, 1.0f);

    for (int t = tid; t < 2048; t += NTH) {
        float2 z  = Zt[pad(t)];
        float2 xv = *(const float2*)(xr + 2 * t);
        *(float2*)(orow + 2 * t) = make_float2(z.x + xv.x, z.y + xv.y);
    }
}

// ---------------------------------------------------------------------------
extern "C" void kernel_launch(void* const* d_in, const int* in_sizes, int n_in,
                              void* d_out, int out_size, void* d_ws, size_t ws_size,
                              hipStream_t stream) {
    const float* x     = (const float*)d_in[0];
    const float* w1_re = (const float*)d_in[1];
    const float* w1_im = (const float*)d_in[2];
    const float* w2_re = (const float*)d_in[3];
    const float* w2_im = (const float*)d_in[4];
    const float* b1_re = (const float*)d_in[5];
    const float* b1_im = (const float*)d_in[6];
    const float* b2_re = (const float*)d_in[7];
    const float* b2_im = (const float*)d_in[8];
    float* out = (float*)d_out;

    k_rfft_fwd<<<12288, NTH, 0, stream>>>(x, out);
    if (ws_size >= (size_t)WS_WT_BYTES) {
        ushort* wt = (ushort*)d_ws;
        k_prep<<<(294912 + NTH - 1) / NTH, NTH, 0, stream>>>(w1_re, w1_im, w2_re, w2_im, wt);
        k_mix5<<<dim3(33, 8, 16), NTH, 0, stream>>>(out, wt, b1_re, b1_im, b2_re, b2_im);
    } else {
        k_mix_fallback<<<dim3(33, 8, 16), NTH, 0, stream>>>(out, w1_re, w1_im, w2_re, w2_im,
                                                            b1_re, b1_im, b2_re, b2_im);
    }
    k_irfft_add<<<12288, NTH, 0, stream>>>(x, out);
}

// Round 6
// 311.690 us; speedup vs baseline: 1.4947x; 1.1973x over previous
//
#include <hip/hip_runtime.h>
#include <math.h>

#define NTH 256
#define LAM 0.01f
#define WS_WT_BYTES 589824   // 4 planes * 8 blocks * 96*96 * 2B (bf16 W^T)

typedef __attribute__((ext_vector_type(8))) short short8;
typedef __attribute__((ext_vector_type(8))) unsigned short ushort8;
typedef __attribute__((ext_vector_type(4))) float f32x4;

__device__ __forceinline__ ushort f2bf(float f) {
    union { float f; unsigned u; } c; c.f = f;
    unsigned u = c.u;
    u += 0x7fffu + ((u >> 16) & 1u);   // round-to-nearest-even
    return (ushort)(u >> 16);
}

// LDS index padding: one extra float2 every 8 -> radix-8's stride-8 scatter
// becomes stride-9 (16 distinct bank-pairs = minimum phases for b64).
__device__ __forceinline__ int pad(int i) { return i + (i >> 3); }
#define FFT_LDS_SZ 2304   // pad(2047)=2302, round up

// ---- complex helpers -------------------------------------------------------
__device__ __forceinline__ float2 cadd(float2 a, float2 b) { return make_float2(a.x + b.x, a.y + b.y); }
__device__ __forceinline__ float2 csub(float2 a, float2 b) { return make_float2(a.x - b.x, a.y - b.y); }
__device__ __forceinline__ float2 cmul(float2 a, float2 b) { return make_float2(a.x * b.x - a.y * b.y, a.x * b.y + a.y * b.x); }
__device__ __forceinline__ float2 cjrot(float2 a, float sign) { return make_float2(-sign * a.y, sign * a.x); } // sign*i*a

// ---------------------------------------------------------------------------
// Radix-8 butterfly on registers (Ns=1 form: no input twiddle).
// ---------------------------------------------------------------------------
__device__ __forceinline__ void radix8_bfly(const float2 t[8], float2 o[8], float sign) {
    float2 apc = cadd(t[0], t[4]), amc = csub(t[0], t[4]);
    float2 bpd = cadd(t[2], t[6]), bmd = csub(t[2], t[6]);
    float2 e0 = cadd(apc, bpd), e2 = csub(apc, bpd);
    float2 jb = cjrot(bmd, sign);
    float2 e1 = cadd(amc, jb), e3 = csub(amc, jb);
    float2 apc2 = cadd(t[1], t[5]), amc2 = csub(t[1], t[5]);
    float2 bpd2 = cadd(t[3], t[7]), bmd2 = csub(t[3], t[7]);
    float2 q0 = cadd(apc2, bpd2), q2 = csub(apc2, bpd2);
    float2 jb2 = cjrot(bmd2, sign);
    float2 q1 = cadd(amc2, jb2), q3 = csub(amc2, jb2);
    const float H = 0.70710678118654752f;
    q1 = cmul(q1, make_float2(H, sign * H));
    q2 = cjrot(q2, sign);
    q3 = cmul(q3, make_float2(-H, sign * H));
    o[0] = cadd(e0, q0); o[1] = cadd(e1, q1); o[2] = cadd(e2, q2); o[3] = cadd(e3, q3);
    o[4] = csub(e0, q0); o[5] = csub(e1, q1); o[6] = csub(e2, q2); o[7] = csub(e3, q3);
}

// ---------------------------------------------------------------------------
// Middle radix-8 Stockham stage (LDS -> LDS), with input twiddles.
// ---------------------------------------------------------------------------
__device__ __forceinline__ void radix8_stage(const float2* __restrict__ src,
                                             float2* __restrict__ dst,
                                             int tid, int Ns, float sign) {
    const int u = tid;                       // 256 butterflies, 256 threads
    const int r = u & (Ns - 1);
    float2 t[8];
    t[0] = src[pad(u)];
    t[1] = src[pad(u + 256)];
    t[2] = src[pad(u + 512)];
    t[3] = src[pad(u + 768)];
    t[4] = src[pad(u + 1024)];
    t[5] = src[pad(u + 1280)];
    t[6] = src[pad(u + 1536)];
    t[7] = src[pad(u + 1792)];
    {
        float ang = sign * ((float)M_PI / (4.0f * (float)Ns)) * (float)r;  // 2*pi*r/(8*Ns)
        float s1, c1;
        __sincosf(ang, &s1, &c1);
        float2 w1 = make_float2(c1, s1);
        float2 w2 = cmul(w1, w1);
        float2 w3 = cmul(w2, w1);
        float2 w4 = cmul(w2, w2);
        float2 w5 = cmul(w4, w1);
        float2 w6 = cmul(w4, w2);
        float2 w7 = cmul(w4, w3);
        t[1] = cmul(t[1], w1); t[2] = cmul(t[2], w2); t[3] = cmul(t[3], w3);
        t[4] = cmul(t[4], w4); t[5] = cmul(t[5], w5); t[6] = cmul(t[6], w6);
        t[7] = cmul(t[7], w7);
    }
    float2 o[8];
    radix8_bfly(t, o, sign);
    const int d = ((u - r) << 3) + r;
    dst[pad(d)]          = o[0];
    dst[pad(d + Ns)]     = o[1];
    dst[pad(d + 2 * Ns)] = o[2];
    dst[pad(d + 3 * Ns)] = o[3];
    dst[pad(d + 4 * Ns)] = o[4];
    dst[pad(d + 5 * Ns)] = o[5];
    dst[pad(d + 6 * Ns)] = o[6];
    dst[pad(d + 7 * Ns)] = o[7];
}

__device__ __forceinline__ void radix4_final(const float2* __restrict__ src,
                                             float2* __restrict__ dst,
                                             int tid, float sign) {
    for (int u = tid; u < 512; u += NTH) {
        float2 x0 = src[pad(u)];
        float2 x1 = src[pad(u + 512)];
        float2 x2 = src[pad(u + 1024)];
        float2 x3 = src[pad(u + 1536)];
        float ang = sign * ((float)M_PI / 1024.0f) * (float)u;   // 2*pi*u/2048
        float s1, c1;
        __sincosf(ang, &s1, &c1);
        float2 w1 = make_float2(c1, s1);
        float2 w2 = cmul(w1, w1);
        float2 w3 = cmul(w2, w1);
        x1 = cmul(x1, w1); x2 = cmul(x2, w2); x3 = cmul(x3, w3);
        float2 apc = cadd(x0, x2), amc = csub(x0, x2);
        float2 bpd = cadd(x1, x3), bmd = csub(x1, x3);
        float2 e = cjrot(bmd, sign);
        dst[pad(u)]        = cadd(apc, bpd);
        dst[pad(u + 512)]  = cadd(amc, e);
        dst[pad(u + 1024)] = csub(apc, bpd);
        dst[pad(u + 1536)] = csub(amc, e);
    }
}

// ---------------------------------------------------------------------------
// Forward rfft per row (ortho), packed output (4096 floats / row).
// Stage 1 fused with global load (no LDS round-trip); 4 barriers.
// ---------------------------------------------------------------------------
__global__ __launch_bounds__(NTH, 4) void k_rfft_fwd(const float* __restrict__ x,
                                                     float* __restrict__ out) {
    __shared__ float2 bufA[FFT_LDS_SZ];
    __shared__ float2 bufB[FFT_LDS_SZ];
    const int row = blockIdx.x;
    const float* xr = x + (size_t)row * 4096;
    float* orow = out + (size_t)row * 4096;
    const int tid = threadIdx.x;

    // ---- fused stage 1 (radix-8, Ns=1) straight from global
    {
        float2 t[8], o[8];
#pragma unroll
        for (int j = 0; j < 8; ++j)
            t[j] = *(const float2*)(xr + 2 * (tid + 256 * j));
        radix8_bfly(t, o, -1.0f);
#pragma unroll
        for (int j = 0; j < 8; ++j)
            bufB[pad(8 * tid + j)] = o[j];
    }
    __syncthreads();
    radix8_stage(bufB, bufA, tid, 8, -1.0f);
    __syncthreads();
    radix8_stage(bufA, bufB, tid, 64, -1.0f);
    __syncthreads();
    radix4_final(bufB, bufA, tid, -1.0f);
    __syncthreads();
    float2* Z = bufA;

    // ---- pack; twiddle chained by rotation of -pi/8 per iteration
    const float scale = 1.0f / 64.0f;
    float s0, c0;
    __sincosf(-(float)M_PI * (float)tid / 2048.0f, &s0, &c0);
    float2 w = make_float2(c0, s0);
    const float2 stepw = make_float2(0.92387953251128674f, -0.38268343236508978f);
    for (int k = tid; k <= 2048; k += NTH) {
        float2 zk = Z[pad(k & 2047)];
        float2 zn = Z[pad((2048 - k) & 2047)];
        float Ar = 0.5f * (zk.x + zn.x), Ai = 0.5f * (zk.y - zn.y);
        float Br = 0.5f * (zk.x - zn.x), Bi = 0.5f * (zk.y + zn.y);
        float wBr = w.x * Br - w.y * Bi;
        float wBi = w.x * Bi + w.y * Br;
        float Xr = (Ar + wBi) * scale;
        float Xi = (Ai - wBr) * scale;
        if (k == 0)          orow[0] = Xr;
        else if (k == 2048)  orow[1] = Xr;
        else                 *(float2*)(orow + 2 * k) = make_float2(Xr, Xi);
        w = cmul(w, stepw);
    }
}

// ---------------------------------------------------------------------------
// Weight preprocessing: fp32 W[a][n][i][o] -> bf16 W^T in ws: [a][n][o][i].
// ---------------------------------------------------------------------------
__global__ __launch_bounds__(NTH) void k_prep(
    const float* __restrict__ w1_re, const float* __restrict__ w1_im,
    const float* __restrict__ w2_re, const float* __restrict__ w2_im,
    ushort* __restrict__ wt) {
    int gid = blockIdx.x * NTH + threadIdx.x;   // 0 .. 294911
    if (gid >= 294912) return;
    int a   = gid / 73728;
    int rem = gid - a * 73728;
    int n   = rem / 9216;
    int r2  = rem - n * 9216;
    int o   = r2 / 96;
    int i   = r2 - o * 96;
    const float* src = (a == 0) ? w1_re : (a == 1) ? w1_im : (a == 2) ? w2_re : w2_im;
    wt[gid] = f2bf(src[(n * 96 + i) * 96 + o]);
}

// ---------------------------------------------------------------------------
// MFMA mixer v5: barrier-free + explicit MLP batching (proven ~125 us).
// ---------------------------------------------------------------------------
__global__ __launch_bounds__(NTH, 3) void k_mix5(
    float* __restrict__ io, const ushort* __restrict__ wt,
    const float* __restrict__ b1_re, const float* __restrict__ b1_im,
    const float* __restrict__ b2_re, const float* __restrict__ b2_im) {
    __shared__ __align__(16) ushort xb[2][64][104];   // 26624 B

    const int mt = blockIdx.x;
    const int n  = blockIdx.y;
    const int b  = blockIdx.z;
    const int tid  = threadIdx.x;
    const int lane = tid & 63;
    const int wv   = tid >> 6;
    const int m0 = mt * 64;
    const int mw = wv * 16;
    float* base = io + ((size_t)b * 768 + (size_t)n * 96) * 4096;

    const int lc = lane & 15;
    const int hi = lane >> 4;

    // ---- stage own 16-mode stripe; batched loads (fast path: interior modes)
    {
        const int m = m0 + mw + lc;            // this lane's mode
        if (m >= 1 && m < 2048) {
            const float* src0 = base + 2 * m;
#pragma unroll
            for (int half = 0; half < 2; ++half) {
                float2 v[12];
#pragma unroll
                for (int t = 0; t < 12; ++t) {
                    const int i = hi + 4 * (12 * half + t);
                    v[t] = *(const float2*)(src0 + (size_t)i * 4096);
                }
#pragma unroll
                for (int t = 0; t < 12; ++t) {
                    const int i = hi + 4 * (12 * half + t);
                    xb[0][mw + lc][i] = f2bf(v[t].x);
                    xb[1][mw + lc][i] = f2bf(v[t].y);
                }
            }
        } else {
            for (int i = hi; i < 96; i += 4) {
                const float* row = base + (size_t)i * 4096;
                float re = 0.f;
                if (m == 0)          re = row[0];
                else if (m == 2048)  re = row[1];
                xb[0][mw + lc][i] = f2bf(re);
                xb[1][mw + lc][i] = 0;
            }
        }
    }

    const int kl = 8 * hi;
    const int mrow = mw + lc;
    const ushort* wn  = wt + (size_t)n * 9216;        // w1_re^T; +73728 per plane
    const ushort* wn2 = wn + 2 * 73728;               // w2_re^T

    float b1r[6], b1i[6];
#pragma unroll
    for (int nt = 0; nt < 6; ++nt) {
        b1r[nt] = b1_re[n * 96 + nt * 16 + lc];
        b1i[nt] = b1_im[n * 96 + nt * 16 + lc];
    }

    f32x4 accR[6], accI[6];
    const f32x4 zero = {0.f, 0.f, 0.f, 0.f};
#pragma unroll
    for (int nt = 0; nt < 6; ++nt) { accR[nt] = zero; accI[nt] = zero; }

    // ---- layer 1: preload 12 weight frags per kk, then 24 MFMAs
#pragma unroll
    for (int kk = 0; kk < 3; ++kk) {
        const int k0 = kk * 32 + kl;
        short8 wr[6], wi[6];
#pragma unroll
        for (int nt = 0; nt < 6; ++nt) {
            const ushort* wp = wn + (nt * 16 + lc) * 96 + k0;
            wr[nt] = *(const short8*)(wp);
            wi[nt] = *(const short8*)(wp + 73728);
        }
        short8 ar = *(const short8*)&xb[0][mrow][k0];
        short8 ai = *(const short8*)&xb[1][mrow][k0];
        short8 nai;
#pragma unroll
        for (int j = 0; j < 8; ++j) nai[j] = ai[j] ^ (short)0x8000;
#pragma unroll
        for (int nt = 0; nt < 6; ++nt) {
            accR[nt] = __builtin_amdgcn_mfma_f32_16x16x32_bf16(ar,  wr[nt], accR[nt], 0, 0, 0);
            accR[nt] = __builtin_amdgcn_mfma_f32_16x16x32_bf16(nai, wi[nt], accR[nt], 0, 0, 0);
            accI[nt] = __builtin_amdgcn_mfma_f32_16x16x32_bf16(ar,  wi[nt], accI[nt], 0, 0, 0);
            accI[nt] = __builtin_amdgcn_mfma_f32_16x16x32_bf16(ai,  wr[nt], accI[nt], 0, 0, 0);
        }
    }
    // crelu -> h into own stripe (same-wave LDS dependency only)
#pragma unroll
    for (int nt = 0; nt < 6; ++nt) {
#pragma unroll
        for (int q = 0; q < 4; ++q) {
            int m = mw + 4 * hi + q;
            xb[0][m][nt * 16 + lc] = f2bf(fmaxf(accR[nt][q] + b1r[nt], 0.f));
            xb[1][m][nt * 16 + lc] = f2bf(fmaxf(accI[nt][q] + b1i[nt], 0.f));
        }
    }

    // ---- layer 2
#pragma unroll
    for (int nt = 0; nt < 6; ++nt) { accR[nt] = zero; accI[nt] = zero; }
#pragma unroll
    for (int kk = 0; kk < 3; ++kk) {
        const int k0 = kk * 32 + kl;
        short8 wr[6], wi[6];
#pragma unroll
        for (int nt = 0; nt < 6; ++nt) {
            const ushort* wp = wn2 + (nt * 16 + lc) * 96 + k0;
            wr[nt] = *(const short8*)(wp);
            wi[nt] = *(const short8*)(wp + 73728);
        }
        short8 ar = *(const short8*)&xb[0][mrow][k0];
        short8 ai = *(const short8*)&xb[1][mrow][k0];
        short8 nai;
#pragma unroll
        for (int j = 0; j < 8; ++j) nai[j] = ai[j] ^ (short)0x8000;
#pragma unroll
        for (int nt = 0; nt < 6; ++nt) {
            accR[nt] = __builtin_amdgcn_mfma_f32_16x16x32_bf16(ar,  wr[nt], accR[nt], 0, 0, 0);
            accR[nt] = __builtin_amdgcn_mfma_f32_16x16x32_bf16(nai, wi[nt], accR[nt], 0, 0, 0);
            accI[nt] = __builtin_amdgcn_mfma_f32_16x16x32_bf16(ar,  wi[nt], accI[nt], 0, 0, 0);
            accI[nt] = __builtin_amdgcn_mfma_f32_16x16x32_bf16(ai,  wr[nt], accI[nt], 0, 0, 0);
        }
    }

    // ---- softshrink + packed store: 4 consecutive modes -> two float4 stores
    float b2r[6], b2i[6];
#pragma unroll
    for (int nt = 0; nt < 6; ++nt) {
        b2r[nt] = b2_re[n * 96 + nt * 16 + lc];
        b2i[nt] = b2_im[n * 96 + nt * 16 + lc];
    }
    const int mq = m0 + mw + 4 * hi;          // first of this lane's 4 modes
#pragma unroll
    for (int nt = 0; nt < 6; ++nt) {
        float sr[4], si[4];
#pragma unroll
        for (int q = 0; q < 4; ++q) {
            float vr = accR[nt][q] + b2r[nt];
            float vi = accI[nt][q] + b2i[nt];
            sr[q] = copysignf(fmaxf(fabsf(vr) - LAM, 0.f), vr);
            si[q] = copysignf(fmaxf(fabsf(vi) - LAM, 0.f), vi);
        }
        float* row = base + (size_t)(nt * 16 + lc) * 4096;
        if (mq >= 1 && mq + 3 < 2048) {
            f32x4 lo = {sr[0], si[0], sr[1], si[1]};
            f32x4 hv = {sr[2], si[2], sr[3], si[3]};
            *(f32x4*)(row + 2 * mq)     = lo;
            *(f32x4*)(row + 2 * mq + 4) = hv;
        } else {
#pragma unroll
            for (int q = 0; q < 4; ++q) {
                int m = mq + q;
                if (m == 0)          row[0] = sr[q];
                else if (m == 2048)  row[1] = sr[q];
                else if (m < 2048)   *(float2*)(row + 2 * m) = make_float2(sr[q], si[q]);
            }
        }
    }
}

// ---------------------------------------------------------------------------
// Fallback mixer (no ws dependency).
// ---------------------------------------------------------------------------
__global__ __launch_bounds__(NTH) void k_mix_fallback(
    float* __restrict__ io,
    const float* __restrict__ w1_re, const float* __restrict__ w1_im,
    const float* __restrict__ w2_re, const float* __restrict__ w2_im,
    const float* __restrict__ b1_re, const float* __restrict__ b1_im,
    const float* __restrict__ b2_re, const float* __restrict__ b2_im) {
    __shared__ __align__(16) ushort xb[2][64][96];
    __shared__ __align__(16) ushort wb[2][96][104];

    const int mt = blockIdx.x;
    const int n  = blockIdx.y;
    const int b  = blockIdx.z;
    const int tid = threadIdx.x;
    const int lane = tid & 63;
    const int wv   = tid >> 6;
    const int m0 = mt * 64;
    float* base = io + ((size_t)b * 768 + (size_t)n * 96) * 4096;

    for (int idx = tid; idx < 96 * 64; idx += NTH) {
        int i = idx >> 6, mm = idx & 63;
        int m = m0 + mm;
        const float* row = base + (size_t)i * 4096;
        float re = 0.f, im = 0.f;
        if (m == 0) { re = row[0]; }
        else if (m == 2048) { re = row[1]; }
        else if (m < 2048) { float2 v = *(const float2*)(row + 2 * m); re = v.x; im = v.y; }
        xb[0][mm][i] = f2bf(re);
        xb[1][mm][i] = f2bf(im);
    }
    const float* W1r = w1_re + (size_t)n * 9216;
    const float* W1i = w1_im + (size_t)n * 9216;
    for (int idx = tid; idx < 9216; idx += NTH) {
        int i = idx / 96, o = idx - i * 96;
        wb[0][o][i] = f2bf(W1r[idx]);
        wb[1][o][i] = f2bf(W1i[idx]);
    }
    const int lc = lane & 15;
    float b1r[6], b1i[6], b2r[6], b2i[6];
#pragma unroll
    for (int nt = 0; nt < 6; ++nt) {
        b1r[nt] = b1_re[n * 96 + nt * 16 + lc];
        b1i[nt] = b1_im[n * 96 + nt * 16 + lc];
        b2r[nt] = b2_re[n * 96 + nt * 16 + lc];
        b2i[nt] = b2_im[n * 96 + nt * 16 + lc];
    }
    __syncthreads();

    const int mw = wv * 16;
    const int klr = 8 * (lane >> 4);
    const int mrow = mw + lc;

    f32x4 accR[6], accI[6];
    const f32x4 zero = {0.f, 0.f, 0.f, 0.f};
#pragma unroll
    for (int nt = 0; nt < 6; ++nt) { accR[nt] = zero; accI[nt] = zero; }

#pragma unroll
    for (int kk = 0; kk < 3; ++kk) {
        int k0 = kk * 32 + klr;
        short8 ar = *(const short8*)&xb[0][mrow][k0];
        short8 ai = *(const short8*)&xb[1][mrow][k0];
        short8 nai;
#pragma unroll
        for (int j = 0; j < 8; ++j) nai[j] = ai[j] ^ (short)0x8000;
#pragma unroll
        for (int nt = 0; nt < 6; ++nt) {
            short8 br = *(const short8*)&wb[0][nt * 16 + lc][k0];
            short8 bi = *(const short8*)&wb[1][nt * 16 + lc][k0];
            accR[nt] = __builtin_amdgcn_mfma_f32_16x16x32_bf16(ar,  br, accR[nt], 0, 0, 0);
            accR[nt] = __builtin_amdgcn_mfma_f32_16x16x32_bf16(nai, bi, accR[nt], 0, 0, 0);
            accI[nt] = __builtin_amdgcn_mfma_f32_16x16x32_bf16(ar,  bi, accI[nt], 0, 0, 0);
            accI[nt] = __builtin_amdgcn_mfma_f32_16x16x32_bf16(ai,  br, accI[nt], 0, 0, 0);
        }
    }
#pragma unroll
    for (int nt = 0; nt < 6; ++nt) {
#pragma unroll
        for (int q = 0; q < 4; ++q) {
            int m = mw + 4 * (lane >> 4) + q;
            float hr = fmaxf(accR[nt][q] + b1r[nt], 0.f);
            float hi = fmaxf(accI[nt][q] + b1i[nt], 0.f);
            xb[0][m][nt * 16 + lc] = f2bf(hr);
            xb[1][m][nt * 16 + lc] = f2bf(hi);
        }
    }
    __syncthreads();

    const float* W2r = w2_re + (size_t)n * 9216;
    const float* W2i = w2_im + (size_t)n * 9216;
    for (int idx = tid; idx < 9216; idx += NTH) {
        int i = idx / 96, o = idx - i * 96;
        wb[0][o][i] = f2bf(W2r[idx]);
        wb[1][o][i] = f2bf(W2i[idx]);
    }
    __syncthreads();

#pragma unroll
    for (int nt = 0; nt < 6; ++nt) { accR[nt] = zero; accI[nt] = zero; }
#pragma unroll
    for (int kk = 0; kk < 3; ++kk) {
        int k0 = kk * 32 + klr;
        short8 ar = *(const short8*)&xb[0][mrow][k0];
        short8 ai = *(const short8*)&xb[1][mrow][k0];
        short8 nai;
#pragma unroll
        for (int j = 0; j < 8; ++j) nai[j] = ai[j] ^ (short)0x8000;
#pragma unroll
        for (int nt = 0; nt < 6; ++nt) {
            short8 br = *(const short8*)&wb[0][nt * 16 + lc][k0];
            short8 bi = *(const short8*)&wb[1][nt * 16 + lc][k0];
            accR[nt] = __builtin_amdgcn_mfma_f32_16x16x32_bf16(ar,  br, accR[nt], 0, 0, 0);
            accR[nt] = __builtin_amdgcn_mfma_f32_16x16x32_bf16(nai, bi, accR[nt], 0, 0, 0);
            accI[nt] = __builtin_amdgcn_mfma_f32_16x16x32_bf16(ar,  bi, accI[nt], 0, 0, 0);
            accI[nt] = __builtin_amdgcn_mfma_f32_16x16x32_bf16(ai,  br, accI[nt], 0, 0, 0);
        }
    }
#pragma unroll
    for (int nt = 0; nt < 6; ++nt) {
#pragma unroll
        for (int q = 0; q < 4; ++q) {
            int m = m0 + mw + 4 * (lane >> 4) + q;
            float vr = accR[nt][q] + b2r[nt];
            float vi = accI[nt][q] + b2i[nt];
            float sr = copysignf(fmaxf(fabsf(vr) - LAM, 0.f), vr);
            float si = copysignf(fmaxf(fabsf(vi) - LAM, 0.f), vi);
            float* row = base + (size_t)(nt * 16 + lc) * 4096;
            if (m == 0)          row[0] = sr;
            else if (m == 2048)  row[1] = sr;
            else if (m < 2048)   *(float2*)(row + 2 * m) = make_float2(sr, si);
        }
    }
}

// ---------------------------------------------------------------------------
// Inverse rfft per row (ortho) + residual add, in-place on packed spectrum.
// Stage 1 (pre-twiddle pack + radix-8) fused with global loads; final radix-4
// fused with residual add + store. 3 barriers, 3 LDS round-trips.
// ---------------------------------------------------------------------------
__global__ __launch_bounds__(NTH, 4) void k_irfft_add(const float* __restrict__ x,
                                                      float* __restrict__ io) {
    __shared__ float2 bufA[FFT_LDS_SZ];
    __shared__ float2 bufB[FFT_LDS_SZ];
    const int row = blockIdx.x;
    const float* xr = x + (size_t)row * 4096;
    float* orow = io + (size_t)row * 4096;
    const int tid = threadIdx.x;
    const float scale = 1.0f / 32.0f;

    // ---- fused: pre-twiddle pack + radix-8 stage 1 (Ns=1) from global
    {
        float2 t[8], o[8];
        // chained twiddle: ang_j = pi*(tid+256j)/2048 = ang0 + j*pi/8
        float s0, c0;
        __sincosf((float)M_PI * (float)tid / 2048.0f, &s0, &c0);
        float2 w = make_float2(c0, s0);
        const float2 stepw = make_float2(0.92387953251128674f, 0.38268343236508978f);
#pragma unroll
        for (int j = 0; j < 8; ++j) {
            const int k = tid + 256 * j;
            float Xr, Xi, Yr, Yi;
            if (k == 0) {
                Xr = orow[0]; Xi = 0.f; Yr = orow[1]; Yi = 0.f;
            } else {
                float2 a  = *(const float2*)(orow + 2 * k);
                float2 bq = *(const float2*)(orow + 2 * (2048 - k));
                Xr = a.x; Xi = a.y; Yr = bq.x; Yi = bq.y;
            }
            float Fer = 0.5f * (Xr + Yr), Fei = 0.5f * (Xi - Yi);
            float Dr  = 0.5f * (Xr - Yr), Di  = 0.5f * (Xi + Yi);
            float For = w.x * Dr - w.y * Di;
            float Foi = w.x * Di + w.y * Dr;
            t[j] = make_float2((Fer - Foi) * scale, (Fei + For) * scale);
            w = cmul(w, stepw);
        }
        radix8_bfly(t, o, 1.0f);
#pragma unroll
        for (int j = 0; j < 8; ++j)
            bufB[pad(8 * tid + j)] = o[j];
    }
    __syncthreads();
    radix8_stage(bufB, bufA, tid, 8, 1.0f);
    __syncthreads();
    radix8_stage(bufA, bufB, tid, 64, 1.0f);
    __syncthreads();

    // ---- fused radix-4 final (Ns=512) + residual add + store
#pragma unroll
    for (int it = 0; it < 2; ++it) {
        const int u = tid + 256 * it;
        float2 x0 = bufB[pad(u)];
        float2 x1 = bufB[pad(u + 512)];
        float2 x2 = bufB[pad(u + 1024)];
        float2 x3 = bufB[pad(u + 1536)];
        float ang = ((float)M_PI / 1024.0f) * (float)u;   // sign=+1
        float s1, c1;
        __sincosf(ang, &s1, &c1);
        float2 w1 = make_float2(c1, s1);
        float2 w2 = cmul(w1, w1);
        float2 w3 = cmul(w2, w1);
        x1 = cmul(x1, w1); x2 = cmul(x2, w2); x3 = cmul(x3, w3);
        float2 apc = cadd(x0, x2), amc = csub(x0, x2);
        float2 bpd = cadd(x1, x3), bmd = csub(x1, x3);
        float2 e = cjrot(bmd, 1.0f);
        float2 y0 = cadd(apc, bpd);
        float2 y1 = cadd(amc, e);
        float2 y2 = csub(apc, bpd);
        float2 y3 = csub(amc, e);
        float2 xv0 = *(const float2*)(xr + 2 * u);
        float2 xv1 = *(const float2*)(xr + 2 * (u + 512));
        float2 xv2 = *(const float2*)(xr + 2 * (u + 1024));
        float2 xv3 = *(const float2*)(xr + 2 * (u + 1536));
        *(float2*)(orow + 2 * u)          = cadd(y0, xv0);
        *(float2*)(orow + 2 * (u + 512))  = cadd(y1, xv1);
        *(float2*)(orow + 2 * (u + 1024)) = cadd(y2, xv2);
        *(float2*)(orow + 2 * (u + 1536)) = cadd(y3, xv3);
    }
}

// ---------------------------------------------------------------------------
extern "C" void kernel_launch(void* const* d_in, const int* in_sizes, int n_in,
                              void* d_out, int out_size, void* d_ws, size_t ws_size,
                              hipStream_t stream) {
    const float* x     = (const float*)d_in[0];
    const float* w1_re = (const float*)d_in[1];
    const float* w1_im = (const float*)d_in[2];
    const float* w2_re = (const float*)d_in[3];
    const float* w2_im = (const float*)d_in[4];
    const float* b1_re = (const float*)d_in[5];
    const float* b1_im = (const float*)d_in[6];
    const float* b2_re = (const float*)d_in[7];
    const float* b2_im = (const float*)d_in[8];
    float* out = (float*)d_out;

    k_rfft_fwd<<<12288, NTH, 0, stream>>>(x, out);
    if (ws_size >= (size_t)WS_WT_BYTES) {
        ushort* wt = (ushort*)d_ws;
        k_prep<<<(294912 + NTH - 1) / NTH, NTH, 0, stream>>>(w1_re, w1_im, w2_re, w2_im, wt);
        k_mix5<<<dim3(33, 8, 16), NTH, 0, stream>>>(out, wt, b1_re, b1_im, b2_re, b2_im);
    } else {
        k_mix_fallback<<<dim3(33, 8, 16), NTH, 0, stream>>>(out, w1_re, w1_im, w2_re, w2_im,
                                                            b1_re, b1_im, b2_re, b2_im);
    }
    k_irfft_add<<<12288, NTH, 0, stream>>>(x, out);
}

// Round 7
// 263.609 us; speedup vs baseline: 1.7673x; 1.1824x over previous
//
#include <hip/hip_runtime.h>
#include <math.h>

#define NTH 256
#define LAM 0.01f
#define WS_WT_BYTES 589824   // 4 planes * 8 blocks * 96*96 * 2B (bf16 W^T)

typedef __attribute__((ext_vector_type(8))) short short8;
typedef __attribute__((ext_vector_type(8))) unsigned short ushort8;
typedef __attribute__((ext_vector_type(4))) float f32x4;
typedef __attribute__((ext_vector_type(4))) unsigned int uint4v;

__device__ __forceinline__ ushort f2bf(float f) {
    union { float f; unsigned u; } c; c.f = f;
    unsigned u = c.u;
    u += 0x7fffu + ((u >> 16) & 1u);   // round-to-nearest-even
    return (ushort)(u >> 16);
}
__device__ __forceinline__ float bf2f(ushort h) {
    union { unsigned u; float f; } c; c.u = ((unsigned)h) << 16; return c.f;
}

// Spectrum storage: packed bf16 (re lo16, im hi16), one uint per mode, in the
// first 8 KB of each row's 16 KB slot. Slot 0 = {re(mode0), re(mode2048)}.

// LDS index padding for FFT stages.
__device__ __forceinline__ int pad(int i) { return i + (i >> 3); }
#define FFT_LDS_SZ 2304

// ---- complex helpers -------------------------------------------------------
__device__ __forceinline__ float2 cadd(float2 a, float2 b) { return make_float2(a.x + b.x, a.y + b.y); }
__device__ __forceinline__ float2 csub(float2 a, float2 b) { return make_float2(a.x - b.x, a.y - b.y); }
__device__ __forceinline__ float2 cmul(float2 a, float2 b) { return make_float2(a.x * b.x - a.y * b.y, a.x * b.y + a.y * b.x); }
__device__ __forceinline__ float2 cjrot(float2 a, float sign) { return make_float2(-sign * a.y, sign * a.x); } // sign*i*a

// ---------------------------------------------------------------------------
// Radix-8 butterfly on registers (Ns=1 form: no input twiddle).
// ---------------------------------------------------------------------------
__device__ __forceinline__ void radix8_bfly(const float2 t[8], float2 o[8], float sign) {
    float2 apc = cadd(t[0], t[4]), amc = csub(t[0], t[4]);
    float2 bpd = cadd(t[2], t[6]), bmd = csub(t[2], t[6]);
    float2 e0 = cadd(apc, bpd), e2 = csub(apc, bpd);
    float2 jb = cjrot(bmd, sign);
    float2 e1 = cadd(amc, jb), e3 = csub(amc, jb);
    float2 apc2 = cadd(t[1], t[5]), amc2 = csub(t[1], t[5]);
    float2 bpd2 = cadd(t[3], t[7]), bmd2 = csub(t[3], t[7]);
    float2 q0 = cadd(apc2, bpd2), q2 = csub(apc2, bpd2);
    float2 jb2 = cjrot(bmd2, sign);
    float2 q1 = cadd(amc2, jb2), q3 = csub(amc2, jb2);
    const float H = 0.70710678118654752f;
    q1 = cmul(q1, make_float2(H, sign * H));
    q2 = cjrot(q2, sign);
    q3 = cmul(q3, make_float2(-H, sign * H));
    o[0] = cadd(e0, q0); o[1] = cadd(e1, q1); o[2] = cadd(e2, q2); o[3] = cadd(e3, q3);
    o[4] = csub(e0, q0); o[5] = csub(e1, q1); o[6] = csub(e2, q2); o[7] = csub(e3, q3);
}

// ---------------------------------------------------------------------------
// Middle radix-8 Stockham stage (LDS -> LDS), with input twiddles.
// ---------------------------------------------------------------------------
__device__ __forceinline__ void radix8_stage(const float2* __restrict__ src,
                                             float2* __restrict__ dst,
                                             int tid, int Ns, float sign) {
    const int u = tid;
    const int r = u & (Ns - 1);
    float2 t[8];
    t[0] = src[pad(u)];
    t[1] = src[pad(u + 256)];
    t[2] = src[pad(u + 512)];
    t[3] = src[pad(u + 768)];
    t[4] = src[pad(u + 1024)];
    t[5] = src[pad(u + 1280)];
    t[6] = src[pad(u + 1536)];
    t[7] = src[pad(u + 1792)];
    {
        float ang = sign * ((float)M_PI / (4.0f * (float)Ns)) * (float)r;
        float s1, c1;
        __sincosf(ang, &s1, &c1);
        float2 w1 = make_float2(c1, s1);
        float2 w2 = cmul(w1, w1);
        float2 w3 = cmul(w2, w1);
        float2 w4 = cmul(w2, w2);
        float2 w5 = cmul(w4, w1);
        float2 w6 = cmul(w4, w2);
        float2 w7 = cmul(w4, w3);
        t[1] = cmul(t[1], w1); t[2] = cmul(t[2], w2); t[3] = cmul(t[3], w3);
        t[4] = cmul(t[4], w4); t[5] = cmul(t[5], w5); t[6] = cmul(t[6], w6);
        t[7] = cmul(t[7], w7);
    }
    float2 o[8];
    radix8_bfly(t, o, sign);
    const int d = ((u - r) << 3) + r;
    dst[pad(d)]          = o[0];
    dst[pad(d + Ns)]     = o[1];
    dst[pad(d + 2 * Ns)] = o[2];
    dst[pad(d + 3 * Ns)] = o[3];
    dst[pad(d + 4 * Ns)] = o[4];
    dst[pad(d + 5 * Ns)] = o[5];
    dst[pad(d + 6 * Ns)] = o[6];
    dst[pad(d + 7 * Ns)] = o[7];
}

__device__ __forceinline__ void radix4_final(const float2* __restrict__ src,
                                             float2* __restrict__ dst,
                                             int tid, float sign) {
    for (int u = tid; u < 512; u += NTH) {
        float2 x0 = src[pad(u)];
        float2 x1 = src[pad(u + 512)];
        float2 x2 = src[pad(u + 1024)];
        float2 x3 = src[pad(u + 1536)];
        float ang = sign * ((float)M_PI / 1024.0f) * (float)u;
        float s1, c1;
        __sincosf(ang, &s1, &c1);
        float2 w1 = make_float2(c1, s1);
        float2 w2 = cmul(w1, w1);
        float2 w3 = cmul(w2, w1);
        x1 = cmul(x1, w1); x2 = cmul(x2, w2); x3 = cmul(x3, w3);
        float2 apc = cadd(x0, x2), amc = csub(x0, x2);
        float2 bpd = cadd(x1, x3), bmd = csub(x1, x3);
        float2 e = cjrot(bmd, sign);
        dst[pad(u)]        = cadd(apc, bpd);
        dst[pad(u + 512)]  = cadd(amc, e);
        dst[pad(u + 1024)] = csub(apc, bpd);
        dst[pad(u + 1536)] = csub(amc, e);
    }
}

// ---------------------------------------------------------------------------
// Forward rfft per row (ortho); output = packed bf16 spectrum (8 KB / row).
// ---------------------------------------------------------------------------
__global__ __launch_bounds__(NTH, 4) void k_rfft_fwd(const float* __restrict__ x,
                                                     float* __restrict__ out) {
    __shared__ float2 bufA[FFT_LDS_SZ];
    __shared__ float2 bufB[FFT_LDS_SZ];
    const int row = blockIdx.x;
    const float* xr = x + (size_t)row * 4096;
    unsigned* srow = (unsigned*)(out + (size_t)row * 4096);
    const int tid = threadIdx.x;

    // ---- fused stage 1 (radix-8, Ns=1) straight from global
    {
        float2 t[8], o[8];
#pragma unroll
        for (int j = 0; j < 8; ++j)
            t[j] = *(const float2*)(xr + 2 * (tid + 256 * j));
        radix8_bfly(t, o, -1.0f);
#pragma unroll
        for (int j = 0; j < 8; ++j)
            bufB[pad(8 * tid + j)] = o[j];
    }
    __syncthreads();
    radix8_stage(bufB, bufA, tid, 8, -1.0f);
    __syncthreads();
    radix8_stage(bufA, bufB, tid, 64, -1.0f);
    __syncthreads();
    radix4_final(bufB, bufA, tid, -1.0f);
    __syncthreads();
    float2* Z = bufA;

    // ---- pack to bf16; twiddle chained by rotation of -pi/8 per iteration
    const float scale = 1.0f / 64.0f;
    float s0, c0;
    __sincosf(-(float)M_PI * (float)tid / 2048.0f, &s0, &c0);
    float2 w = make_float2(c0, s0);
    const float2 stepw = make_float2(0.92387953251128674f, -0.38268343236508978f);
    for (int k = tid; k <= 2048; k += NTH) {
        float2 zk = Z[pad(k & 2047)];
        float2 zn = Z[pad((2048 - k) & 2047)];
        float Ar = 0.5f * (zk.x + zn.x), Ai = 0.5f * (zk.y - zn.y);
        float Br = 0.5f * (zk.x - zn.x), Bi = 0.5f * (zk.y + zn.y);
        float wBr = w.x * Br - w.y * Bi;
        float wBi = w.x * Bi + w.y * Br;
        float Xr = (Ar + wBi) * scale;
        float Xi = (Ai - wBr) * scale;
        if (k == 0)          ((ushort*)srow)[0] = f2bf(Xr);
        else if (k == 2048)  ((ushort*)srow)[1] = f2bf(Xr);
        else                 srow[k] = (unsigned)f2bf(Xr) | ((unsigned)f2bf(Xi) << 16);
        w = cmul(w, stepw);
    }
}

// ---------------------------------------------------------------------------
// Weight preprocessing: fp32 W[a][n][i][o] -> bf16 W^T in ws: [a][n][o][i].
// ---------------------------------------------------------------------------
__global__ __launch_bounds__(NTH) void k_prep(
    const float* __restrict__ w1_re, const float* __restrict__ w1_im,
    const float* __restrict__ w2_re, const float* __restrict__ w2_im,
    ushort* __restrict__ wt) {
    int gid = blockIdx.x * NTH + threadIdx.x;   // 0 .. 294911
    if (gid >= 294912) return;
    int a   = gid / 73728;
    int rem = gid - a * 73728;
    int n   = rem / 9216;
    int r2  = rem - n * 9216;
    int o   = r2 / 96;
    int i   = r2 - o * 96;
    const float* src = (a == 0) ? w1_re : (a == 1) ? w1_im : (a == 2) ? w2_re : w2_im;
    wt[gid] = f2bf(src[(n * 96 + i) * 96 + o]);
}

// ---------------------------------------------------------------------------
// MFMA mixer v6: mix5 structure, bf16 packed spectrum io.
//  - stage: one uint load per channel (bf16 pair), straight to LDS, no cvt.
//  - epilogue: 4 consecutive modes packed into ONE 16-B uint4 store per nt.
// Grid (33, 8, 16) x 256 thr (4 waves), barrier-free.
// ---------------------------------------------------------------------------
__global__ __launch_bounds__(NTH, 3) void k_mix6(
    float* __restrict__ io, const ushort* __restrict__ wt,
    const float* __restrict__ b1_re, const float* __restrict__ b1_im,
    const float* __restrict__ b2_re, const float* __restrict__ b2_im) {
    __shared__ __align__(16) ushort xb[2][64][104];   // 26624 B

    const int mt = blockIdx.x;
    const int n  = blockIdx.y;
    const int b  = blockIdx.z;
    const int tid  = threadIdx.x;
    const int lane = tid & 63;
    const int wv   = tid >> 6;
    const int m0 = mt * 64;
    const int mw = wv * 16;
    unsigned* sb = (unsigned*)(io + ((size_t)b * 768 + (size_t)n * 96) * 4096);

    const int lc = lane & 15;
    const int hi = lane >> 4;

    // ---- stage own 16-mode stripe (batched uint loads, no conversion)
    {
        const int m = m0 + mw + lc;            // this lane's mode
        if (m >= 1 && m < 2048) {
            const unsigned* src0 = sb + m;
#pragma unroll
            for (int half = 0; half < 2; ++half) {
                unsigned v[12];
#pragma unroll
                for (int t = 0; t < 12; ++t) {
                    const int i = hi + 4 * (12 * half + t);
                    v[t] = src0[(size_t)i * 4096];
                }
#pragma unroll
                for (int t = 0; t < 12; ++t) {
                    const int i = hi + 4 * (12 * half + t);
                    xb[0][mw + lc][i] = (ushort)v[t];
                    xb[1][mw + lc][i] = (ushort)(v[t] >> 16);
                }
            }
        } else {
            for (int i = hi; i < 96; i += 4) {
                const ushort* rw = (const ushort*)(sb + (size_t)i * 4096);
                ushort re16 = 0;
                if (m == 0)          re16 = rw[0];
                else if (m == 2048)  re16 = rw[1];
                xb[0][mw + lc][i] = re16;
                xb[1][mw + lc][i] = 0;
            }
        }
    }

    const int kl = 8 * hi;
    const int mrow = mw + lc;
    const ushort* wn  = wt + (size_t)n * 9216;        // w1_re^T; +73728 per plane
    const ushort* wn2 = wn + 2 * 73728;               // w2_re^T

    float b1r[6], b1i[6];
#pragma unroll
    for (int nt = 0; nt < 6; ++nt) {
        b1r[nt] = b1_re[n * 96 + nt * 16 + lc];
        b1i[nt] = b1_im[n * 96 + nt * 16 + lc];
    }

    f32x4 accR[6], accI[6];
    const f32x4 zero = {0.f, 0.f, 0.f, 0.f};
#pragma unroll
    for (int nt = 0; nt < 6; ++nt) { accR[nt] = zero; accI[nt] = zero; }

    // ---- layer 1: preload 12 weight frags per kk, then 24 MFMAs
#pragma unroll
    for (int kk = 0; kk < 3; ++kk) {
        const int k0 = kk * 32 + kl;
        short8 wr[6], wi[6];
#pragma unroll
        for (int nt = 0; nt < 6; ++nt) {
            const ushort* wp = wn + (nt * 16 + lc) * 96 + k0;
            wr[nt] = *(const short8*)(wp);
            wi[nt] = *(const short8*)(wp + 73728);
        }
        short8 ar = *(const short8*)&xb[0][mrow][k0];
        short8 ai = *(const short8*)&xb[1][mrow][k0];
        short8 nai;
#pragma unroll
        for (int j = 0; j < 8; ++j) nai[j] = ai[j] ^ (short)0x8000;
#pragma unroll
        for (int nt = 0; nt < 6; ++nt) {
            accR[nt] = __builtin_amdgcn_mfma_f32_16x16x32_bf16(ar,  wr[nt], accR[nt], 0, 0, 0);
            accR[nt] = __builtin_amdgcn_mfma_f32_16x16x32_bf16(nai, wi[nt], accR[nt], 0, 0, 0);
            accI[nt] = __builtin_amdgcn_mfma_f32_16x16x32_bf16(ar,  wi[nt], accI[nt], 0, 0, 0);
            accI[nt] = __builtin_amdgcn_mfma_f32_16x16x32_bf16(ai,  wr[nt], accI[nt], 0, 0, 0);
        }
    }
    // crelu -> h into own stripe (same-wave LDS dependency only)
#pragma unroll
    for (int nt = 0; nt < 6; ++nt) {
#pragma unroll
        for (int q = 0; q < 4; ++q) {
            int m = mw + 4 * hi + q;
            xb[0][m][nt * 16 + lc] = f2bf(fmaxf(accR[nt][q] + b1r[nt], 0.f));
            xb[1][m][nt * 16 + lc] = f2bf(fmaxf(accI[nt][q] + b1i[nt], 0.f));
        }
    }

    // ---- layer 2
#pragma unroll
    for (int nt = 0; nt < 6; ++nt) { accR[nt] = zero; accI[nt] = zero; }
#pragma unroll
    for (int kk = 0; kk < 3; ++kk) {
        const int k0 = kk * 32 + kl;
        short8 wr[6], wi[6];
#pragma unroll
        for (int nt = 0; nt < 6; ++nt) {
            const ushort* wp = wn2 + (nt * 16 + lc) * 96 + k0;
            wr[nt] = *(const short8*)(wp);
            wi[nt] = *(const short8*)(wp + 73728);
        }
        short8 ar = *(const short8*)&xb[0][mrow][k0];
        short8 ai = *(const short8*)&xb[1][mrow][k0];
        short8 nai;
#pragma unroll
        for (int j = 0; j < 8; ++j) nai[j] = ai[j] ^ (short)0x8000;
#pragma unroll
        for (int nt = 0; nt < 6; ++nt) {
            accR[nt] = __builtin_amdgcn_mfma_f32_16x16x32_bf16(ar,  wr[nt], accR[nt], 0, 0, 0);
            accR[nt] = __builtin_amdgcn_mfma_f32_16x16x32_bf16(nai, wi[nt], accR[nt], 0, 0, 0);
            accI[nt] = __builtin_amdgcn_mfma_f32_16x16x32_bf16(ar,  wi[nt], accI[nt], 0, 0, 0);
            accI[nt] = __builtin_amdgcn_mfma_f32_16x16x32_bf16(ai,  wr[nt], accI[nt], 0, 0, 0);
        }
    }

    // ---- softshrink + packed bf16 store: 4 modes -> one 16-B store per nt
    float b2r[6], b2i[6];
#pragma unroll
    for (int nt = 0; nt < 6; ++nt) {
        b2r[nt] = b2_re[n * 96 + nt * 16 + lc];
        b2i[nt] = b2_im[n * 96 + nt * 16 + lc];
    }
    const int mq = m0 + mw + 4 * hi;          // first of this lane's 4 modes
#pragma unroll
    for (int nt = 0; nt < 6; ++nt) {
        float sr[4], si[4];
#pragma unroll
        for (int q = 0; q < 4; ++q) {
            float vr = accR[nt][q] + b2r[nt];
            float vi = accI[nt][q] + b2i[nt];
            sr[q] = copysignf(fmaxf(fabsf(vr) - LAM, 0.f), vr);
            si[q] = copysignf(fmaxf(fabsf(vi) - LAM, 0.f), vi);
        }
        unsigned* row = sb + (size_t)(nt * 16 + lc) * 4096;
        if (mq >= 1 && mq + 3 < 2048) {
            uint4v pk;
#pragma unroll
            for (int q = 0; q < 4; ++q)
                pk[q] = (unsigned)f2bf(sr[q]) | ((unsigned)f2bf(si[q]) << 16);
            *(uint4v*)(row + mq) = pk;
        } else {
#pragma unroll
            for (int q = 0; q < 4; ++q) {
                int m = mq + q;
                if (m == 0)          ((ushort*)row)[0] = f2bf(sr[q]);
                else if (m == 2048)  ((ushort*)row)[1] = f2bf(sr[q]);
                else if (m < 2048)   row[m] = (unsigned)f2bf(sr[q]) | ((unsigned)f2bf(si[q]) << 16);
            }
        }
    }
}

// ---------------------------------------------------------------------------
// Fallback mixer (no ws dependency), bf16 packed spectrum io.
// ---------------------------------------------------------------------------
__global__ __launch_bounds__(NTH) void k_mix_fallback(
    float* __restrict__ io,
    const float* __restrict__ w1_re, const float* __restrict__ w1_im,
    const float* __restrict__ w2_re, const float* __restrict__ w2_im,
    const float* __restrict__ b1_re, const float* __restrict__ b1_im,
    const float* __restrict__ b2_re, const float* __restrict__ b2_im) {
    __shared__ __align__(16) ushort xb[2][64][96];
    __shared__ __align__(16) ushort wb[2][96][104];

    const int mt = blockIdx.x;
    const int n  = blockIdx.y;
    const int b  = blockIdx.z;
    const int tid = threadIdx.x;
    const int lane = tid & 63;
    const int wv   = tid >> 6;
    const int m0 = mt * 64;
    unsigned* sb = (unsigned*)(io + ((size_t)b * 768 + (size_t)n * 96) * 4096);

    for (int idx = tid; idx < 96 * 64; idx += NTH) {
        int i = idx >> 6, mm = idx & 63;
        int m = m0 + mm;
        const unsigned* row = sb + (size_t)i * 4096;
        ushort re = 0, im = 0;
        if (m == 0) { re = ((const ushort*)row)[0]; }
        else if (m == 2048) { re = ((const ushort*)row)[1]; }
        else if (m < 2048) { unsigned v = row[m]; re = (ushort)v; im = (ushort)(v >> 16); }
        xb[0][mm][i] = re;
        xb[1][mm][i] = im;
    }
    const float* W1r = w1_re + (size_t)n * 9216;
    const float* W1i = w1_im + (size_t)n * 9216;
    for (int idx = tid; idx < 9216; idx += NTH) {
        int i = idx / 96, o = idx - i * 96;
        wb[0][o][i] = f2bf(W1r[idx]);
        wb[1][o][i] = f2bf(W1i[idx]);
    }
    const int lc = lane & 15;
    float b1r[6], b1i[6], b2r[6], b2i[6];
#pragma unroll
    for (int nt = 0; nt < 6; ++nt) {
        b1r[nt] = b1_re[n * 96 + nt * 16 + lc];
        b1i[nt] = b1_im[n * 96 + nt * 16 + lc];
        b2r[nt] = b2_re[n * 96 + nt * 16 + lc];
        b2i[nt] = b2_im[n * 96 + nt * 16 + lc];
    }
    __syncthreads();

    const int mw = wv * 16;
    const int klr = 8 * (lane >> 4);
    const int mrow = mw + lc;

    f32x4 accR[6], accI[6];
    const f32x4 zero = {0.f, 0.f, 0.f, 0.f};
#pragma unroll
    for (int nt = 0; nt < 6; ++nt) { accR[nt] = zero; accI[nt] = zero; }

#pragma unroll
    for (int kk = 0; kk < 3; ++kk) {
        int k0 = kk * 32 + klr;
        short8 ar = *(const short8*)&xb[0][mrow][k0];
        short8 ai = *(const short8*)&xb[1][mrow][k0];
        short8 nai;
#pragma unroll
        for (int j = 0; j < 8; ++j) nai[j] = ai[j] ^ (short)0x8000;
#pragma unroll
        for (int nt = 0; nt < 6; ++nt) {
            short8 br = *(const short8*)&wb[0][nt * 16 + lc][k0];
            short8 bi = *(const short8*)&wb[1][nt * 16 + lc][k0];
            accR[nt] = __builtin_amdgcn_mfma_f32_16x16x32_bf16(ar,  br, accR[nt], 0, 0, 0);
            accR[nt] = __builtin_amdgcn_mfma_f32_16x16x32_bf16(nai, bi, accR[nt], 0, 0, 0);
            accI[nt] = __builtin_amdgcn_mfma_f32_16x16x32_bf16(ar,  bi, accI[nt], 0, 0, 0);
            accI[nt] = __builtin_amdgcn_mfma_f32_16x16x32_bf16(ai,  br, accI[nt], 0, 0, 0);
        }
    }
#pragma unroll
    for (int nt = 0; nt < 6; ++nt) {
#pragma unroll
        for (int q = 0; q < 4; ++q) {
            int m = mw + 4 * (lane >> 4) + q;
            float hr = fmaxf(accR[nt][q] + b1r[nt], 0.f);
            float hi2 = fmaxf(accI[nt][q] + b1i[nt], 0.f);
            xb[0][m][nt * 16 + lc] = f2bf(hr);
            xb[1][m][nt * 16 + lc] = f2bf(hi2);
        }
    }
    __syncthreads();

    const float* W2r = w2_re + (size_t)n * 9216;
    const float* W2i = w2_im + (size_t)n * 9216;
    for (int idx = tid; idx < 9216; idx += NTH) {
        int i = idx / 96, o = idx - i * 96;
        wb[0][o][i] = f2bf(W2r[idx]);
        wb[1][o][i] = f2bf(W2i[idx]);
    }
    __syncthreads();

#pragma unroll
    for (int nt = 0; nt < 6; ++nt) { accR[nt] = zero; accI[nt] = zero; }
#pragma unroll
    for (int kk = 0; kk < 3; ++kk) {
        int k0 = kk * 32 + klr;
        short8 ar = *(const short8*)&xb[0][mrow][k0];
        short8 ai = *(const short8*)&xb[1][mrow][k0];
        short8 nai;
#pragma unroll
        for (int j = 0; j < 8; ++j) nai[j] = ai[j] ^ (short)0x8000;
#pragma unroll
        for (int nt = 0; nt < 6; ++nt) {
            short8 br = *(const short8*)&wb[0][nt * 16 + lc][k0];
            short8 bi = *(const short8*)&wb[1][nt * 16 + lc][k0];
            accR[nt] = __builtin_amdgcn_mfma_f32_16x16x32_bf16(ar,  br, accR[nt], 0, 0, 0);
            accR[nt] = __builtin_amdgcn_mfma_f32_16x16x32_bf16(nai, bi, accR[nt], 0, 0, 0);
            accI[nt] = __builtin_amdgcn_mfma_f32_16x16x32_bf16(ar,  bi, accI[nt], 0, 0, 0);
            accI[nt] = __builtin_amdgcn_mfma_f32_16x16x32_bf16(ai,  br, accI[nt], 0, 0, 0);
        }
    }
#pragma unroll
    for (int nt = 0; nt < 6; ++nt) {
#pragma unroll
        for (int q = 0; q < 4; ++q) {
            int m = m0 + mw + 4 * (lane >> 4) + q;
            float vr = accR[nt][q] + b2r[nt];
            float vi = accI[nt][q] + b2i[nt];
            float sr = copysignf(fmaxf(fabsf(vr) - LAM, 0.f), vr);
            float si = copysignf(fmaxf(fabsf(vi) - LAM, 0.f), vi);
            unsigned* row = sb + (size_t)(nt * 16 + lc) * 4096;
            if (m == 0)          ((ushort*)row)[0] = f2bf(sr);
            else if (m == 2048)  ((ushort*)row)[1] = f2bf(sr);
            else if (m < 2048)   row[m] = (unsigned)f2bf(sr) | ((unsigned)f2bf(si) << 16);
        }
    }
}

// ---------------------------------------------------------------------------
// Inverse rfft per row (ortho) + residual add. Reads packed bf16 spectrum
// (8 KB head of the row), writes fp32 time signal (full 16 KB) in place.
// All spectrum reads happen in fused stage 1, before any store.
// ---------------------------------------------------------------------------
__global__ __launch_bounds__(NTH, 4) void k_irfft_add(const float* __restrict__ x,
                                                      float* __restrict__ io) {
    __shared__ float2 bufA[FFT_LDS_SZ];
    __shared__ float2 bufB[FFT_LDS_SZ];
    const int row = blockIdx.x;
    const float* xr = x + (size_t)row * 4096;
    float* orow = io + (size_t)row * 4096;
    const unsigned* srow = (const unsigned*)orow;
    const int tid = threadIdx.x;
    const float scale = 1.0f / 32.0f;

    // ---- fused: pre-twiddle pack + radix-8 stage 1 (Ns=1) from bf16 spectrum
    {
        float2 t[8], o[8];
        float s0, c0;
        __sincosf((float)M_PI * (float)tid / 2048.0f, &s0, &c0);
        float2 w = make_float2(c0, s0);
        const float2 stepw = make_float2(0.92387953251128674f, 0.38268343236508978f);
#pragma unroll
        for (int j = 0; j < 8; ++j) {
            const int k = tid + 256 * j;
            float Xr, Xi, Yr, Yi;
            if (k == 0) {
                unsigned v0 = srow[0];
                Xr = bf2f((ushort)v0); Xi = 0.f;
                Yr = bf2f((ushort)(v0 >> 16)); Yi = 0.f;
            } else {
                unsigned a  = srow[k];
                unsigned bq = srow[2048 - k];
                Xr = bf2f((ushort)a);  Xi = bf2f((ushort)(a >> 16));
                Yr = bf2f((ushort)bq); Yi = bf2f((ushort)(bq >> 16));
            }
            float Fer = 0.5f * (Xr + Yr), Fei = 0.5f * (Xi - Yi);
            float Dr  = 0.5f * (Xr - Yr), Di  = 0.5f * (Xi + Yi);
            float For = w.x * Dr - w.y * Di;
            float Foi = w.x * Di + w.y * Dr;
            t[j] = make_float2((Fer - Foi) * scale, (Fei + For) * scale);
            w = cmul(w, stepw);
        }
        radix8_bfly(t, o, 1.0f);
#pragma unroll
        for (int j = 0; j < 8; ++j)
            bufB[pad(8 * tid + j)] = o[j];
    }
    __syncthreads();
    radix8_stage(bufB, bufA, tid, 8, 1.0f);
    __syncthreads();
    radix8_stage(bufA, bufB, tid, 64, 1.0f);
    __syncthreads();

    // ---- fused radix-4 final (Ns=512) + residual add + store
#pragma unroll
    for (int it = 0; it < 2; ++it) {
        const int u = tid + 256 * it;
        float2 x0 = bufB[pad(u)];
        float2 x1 = bufB[pad(u + 512)];
        float2 x2 = bufB[pad(u + 1024)];
        float2 x3 = bufB[pad(u + 1536)];
        float ang = ((float)M_PI / 1024.0f) * (float)u;
        float s1, c1;
        __sincosf(ang, &s1, &c1);
        float2 w1 = make_float2(c1, s1);
        float2 w2 = cmul(w1, w1);
        float2 w3 = cmul(w2, w1);
        x1 = cmul(x1, w1); x2 = cmul(x2, w2); x3 = cmul(x3, w3);
        float2 apc = cadd(x0, x2), amc = csub(x0, x2);
        float2 bpd = cadd(x1, x3), bmd = csub(x1, x3);
        float2 e = cjrot(bmd, 1.0f);
        float2 y0 = cadd(apc, bpd);
        float2 y1 = cadd(amc, e);
        float2 y2 = csub(apc, bpd);
        float2 y3 = csub(amc, e);
        float2 xv0 = *(const float2*)(xr + 2 * u);
        float2 xv1 = *(const float2*)(xr + 2 * (u + 512));
        float2 xv2 = *(const float2*)(xr + 2 * (u + 1024));
        float2 xv3 = *(const float2*)(xr + 2 * (u + 1536));
        *(float2*)(orow + 2 * u)          = cadd(y0, xv0);
        *(float2*)(orow + 2 * (u + 512))  = cadd(y1, xv1);
        *(float2*)(orow + 2 * (u + 1024)) = cadd(y2, xv2);
        *(float2*)(orow + 2 * (u + 1536)) = cadd(y3, xv3);
    }
}

// ---------------------------------------------------------------------------
extern "C" void kernel_launch(void* const* d_in, const int* in_sizes, int n_in,
                              void* d_out, int out_size, void* d_ws, size_t ws_size,
                              hipStream_t stream) {
    const float* x     = (const float*)d_in[0];
    const float* w1_re = (const float*)d_in[1];
    const float* w1_im = (const float*)d_in[2];
    const float* w2_re = (const float*)d_in[3];
    const float* w2_im = (const float*)d_in[4];
    const float* b1_re = (const float*)d_in[5];
    const float* b1_im = (const float*)d_in[6];
    const float* b2_re = (const float*)d_in[7];
    const float* b2_im = (const float*)d_in[8];
    float* out = (float*)d_out;

    k_rfft_fwd<<<12288, NTH, 0, stream>>>(x, out);
    if (ws_size >= (size_t)WS_WT_BYTES) {
        ushort* wt = (ushort*)d_ws;
        k_prep<<<(294912 + NTH - 1) / NTH, NTH, 0, stream>>>(w1_re, w1_im, w2_re, w2_im, wt);
        k_mix6<<<dim3(33, 8, 16), NTH, 0, stream>>>(out, wt, b1_re, b1_im, b2_re, b2_im);
    } else {
        k_mix_fallback<<<dim3(33, 8, 16), NTH, 0, stream>>>(out, w1_re, w1_im, w2_re, w2_im,
                                                            b1_re, b1_im, b2_re, b2_im);
    }
    k_irfft_add<<<12288, NTH, 0, stream>>>(x, out);
}